// Round 12
// baseline (1015.609 us; speedup 1.0000x reference)
//
#include <hip/hip_runtime.h>

#define NN 50000
#define EE 800000
#define HD 256
#define NSEG (2 * NN)
#define CHUNK 2048
#define NB ((NSEG + CHUNK - 1) / CHUNK)

typedef unsigned short u16;
typedef unsigned long long u64;
typedef short bf16x8 __attribute__((ext_vector_type(8)));
typedef float f32x4 __attribute__((ext_vector_type(4)));

__device__ __forceinline__ u16 f2bf_rne(float f) {
    unsigned u = __float_as_uint(f);
    return (u16)((u + 0x7FFF + ((u >> 16) & 1)) >> 16);
}
// trunc hi + RNE residual: (h,l) represents v to ~2^-17 relative
__device__ __forceinline__ void split_tr(float v, u16& h, u16& l) {
    unsigned u = __float_as_uint(v);
    h = (u16)(u >> 16);
    l = f2bf_rne(v - __uint_as_float(u & 0xFFFF0000u));
}

// bijective XCD-chunked swizzle (m204)
__device__ __forceinline__ int xcd_swizzle(int orig, int nwg) {
    int q = nwg >> 3, r = nwg & 7;
    int xcd = orig & 7, idx = orig >> 3;
    return (xcd < r ? xcd * (q + 1) : r * (q + 1) + (xcd - r) * q) + idx;
}

// ===================== wave-autonomous dual-projection GEMM (K=768) =====================
// No barriers. Each wave: 32 rows x 64 cols. A f32 coalesced->regs->convert->private LDS;
// B bf16 [64][768] fragment-loaded per-lane direct from global (L2-hot).
// LDS row stride 40 u16 (pad) -> <=2-way banks. lrelu, bf16-pair out.
__global__ __launch_bounds__(256) void gemm_projW(
    const float* __restrict__ A0, const float* __restrict__ A1,
    const u16* __restrict__ B0, const u16* __restrict__ B1,
    const float* __restrict__ bias0, const float* __restrict__ bias1,
    u16* __restrict__ Ch, u16* __restrict__ Cl)
{
    __shared__ __align__(16) u16 lds[4 * 2 * 2 * 1280];   // [wave][buf][h/l][32*40]
    const int p = blockIdx.x & 1;
    const float* __restrict__ A = p ? A1 : A0;
    const u16* __restrict__ Bp = p ? B1 : B0;
    const float* __restrict__ bias = p ? bias1 : bias0;
    const int coff = p * 64;
    const int tid = threadIdx.x, lane = tid & 63, w = tid >> 6;
    const int wrow = (blockIdx.x >> 1) * 128 + w * 32;
    const int r15 = lane & 15, g = lane >> 4;
    const int lbase = w * 2 * 2 * 1280;

    size_t aoff[4];
#pragma unroll
    for (int i = 0; i < 4; i++) {
        int row = wrow + (lane >> 3) + 8 * i;
        row = row < NN ? row : NN - 1;
        aoff[i] = (size_t)row * 768 + (lane & 7) * 4;
    }
    size_t boff[4];
#pragma unroll
    for (int ni = 0; ni < 4; ni++)
        boff[ni] = (size_t)(ni * 16 + r15) * 768 + g * 8;

    f32x4 acc[2][4];
#pragma unroll
    for (int mi = 0; mi < 2; mi++)
#pragma unroll
        for (int ni = 0; ni < 4; ni++) acc[mi][ni] = (f32x4){0.f, 0.f, 0.f, 0.f};

    float4 Ar0[4], Ar1[4];
    uint4 Bs0[4], Bs1[4];

    auto loadA = [&](int t, float4 (&d)[4]) {
#pragma unroll
        for (int i = 0; i < 4; i++) d[i] = *(const float4*)&A[aoff[i] + t * 32];
    };
    auto loadB = [&](int t, uint4 (&d)[4]) {
#pragma unroll
        for (int ni = 0; ni < 4; ni++) d[ni] = *(const uint4*)&Bp[boff[ni] + t * 32];
    };
    auto writeA = [&](const float4 (&s)[4], int buf) {
#pragma unroll
        for (int i = 0; i < 4; i++) {
            int row2 = (lane >> 3) + 8 * i;
            unsigned e0 = __float_as_uint(s[i].x), e1 = __float_as_uint(s[i].y),
                     e2 = __float_as_uint(s[i].z), e3 = __float_as_uint(s[i].w);
            unsigned h0 = __builtin_amdgcn_perm(e1, e0, 0x07060302u);
            unsigned h1 = __builtin_amdgcn_perm(e3, e2, 0x07060302u);
            unsigned q0 = __float_as_uint(s[i].x - __uint_as_float(e0 & 0xFFFF0000u));
            unsigned q1 = __float_as_uint(s[i].y - __uint_as_float(e1 & 0xFFFF0000u));
            unsigned q2 = __float_as_uint(s[i].z - __uint_as_float(e2 & 0xFFFF0000u));
            unsigned q3 = __float_as_uint(s[i].w - __uint_as_float(e3 & 0xFFFF0000u));
            unsigned l0 = __builtin_amdgcn_perm(q1, q0, 0x07060302u);
            unsigned l1 = __builtin_amdgcn_perm(q3, q2, 0x07060302u);
            int idx = lbase + buf * 2 * 1280 + row2 * 40 + (lane & 7) * 4;
            *(u64*)&lds[idx] = (u64)h0 | ((u64)h1 << 32);
            *(u64*)&lds[idx + 1280] = (u64)l0 | ((u64)l1 << 32);
        }
    };
    auto compute = [&](int buf, const uint4 (&Bv)[4]) {
        bf16x8 afh[2], afl[2];
#pragma unroll
        for (int mi = 0; mi < 2; mi++) {
            int row = mi * 16 + r15;
            int idx = lbase + buf * 2 * 1280 + row * 40 + g * 8;
            afh[mi] = *(const bf16x8*)&lds[idx];
            afl[mi] = *(const bf16x8*)&lds[idx + 1280];
        }
#pragma unroll
        for (int mi = 0; mi < 2; mi++)
#pragma unroll
            for (int ni = 0; ni < 4; ni++) {
                bf16x8 bb = __builtin_bit_cast(bf16x8, Bv[ni]);
                acc[mi][ni] = __builtin_amdgcn_mfma_f32_16x16x32_bf16(afh[mi], bb, acc[mi][ni], 0, 0, 0);
                acc[mi][ni] = __builtin_amdgcn_mfma_f32_16x16x32_bf16(afl[mi], bb, acc[mi][ni], 0, 0, 0);
            }
    };

    // prologue
    loadA(0, Ar0); loadB(0, Bs0);
    writeA(Ar0, 0);
    loadA(1, Ar1); loadB(1, Bs1);
    // steady: t = 0..21 (NT=24), all loads in-range
    for (int tt = 0; tt < 11; ++tt) {
        int t0 = 2 * tt;
        loadA(t0 + 2, Ar0);
        compute(0, Bs0);
        loadB(t0 + 2, Bs0);
        writeA(Ar1, 1);
        loadA(t0 + 3, Ar1);
        compute(1, Bs1);
        loadB(t0 + 3, Bs1);
        writeA(Ar0, 0);
    }
    compute(0, Bs0);     // t=22
    writeA(Ar1, 1);      // tile 23 -> buf1
    compute(1, Bs1);     // t=23

#pragma unroll
    for (int mi = 0; mi < 2; mi++) {
#pragma unroll
        for (int ni = 0; ni < 4; ni++) {
            int col = ni * 16 + r15;
            float bsv = bias[col];
            int rbase = wrow + mi * 16 + g * 4;
#pragma unroll
            for (int r = 0; r < 4; r++) {
                int grow = rbase + r;
                if (grow >= NN) continue;
                float v = acc[mi][ni][r] + bsv;
                v = v > 0.f ? v : 0.01f * v;   // lrelu
                u16 h, l; split_tr(v, h, l);
                Ch[(size_t)grow * HD + coff + col] = h;
                Cl[(size_t)grow * HD + coff + col] = l;
            }
        }
    }
}

// ===================== wave-autonomous bf16-pair GEMM (K=256) =====================
// No barriers. Wave: 32 rows x 64 cols. A (h,l) coalesced->regs->private LDS; B direct.
// acc = Ah*B + Al*B. MODE 1: lrelu -> bf16 pair. MODE 2: relu; col<512 -> hrel; else f32.
template<int MODE>
__global__ __launch_bounds__(256) void gemm_waveB(
    const u16* __restrict__ Ahg, const u16* __restrict__ Alg,
    const u16* __restrict__ Bg,
    const float* __restrict__ bias,
    u16* __restrict__ O1h, u16* __restrict__ O1l, float* __restrict__ O2,
    int M, int nxb)
{
    __shared__ __align__(16) u16 lds[4 * 2 * 2 * 1280];
    const int wgid = xcd_swizzle(blockIdx.x, gridDim.x);
    const int brow = (wgid / nxb) * 128, bcol = (wgid % nxb) * 64;
    const int tid = threadIdx.x, lane = tid & 63, w = tid >> 6;
    const int wrow = brow + w * 32;
    const int r15 = lane & 15, g = lane >> 4;
    const int lbase = w * 2 * 2 * 1280;

    size_t aoff[2];
#pragma unroll
    for (int i = 0; i < 2; i++) {
        int row = wrow + (lane >> 2) + 16 * i;
        row = row < M ? row : M - 1;
        aoff[i] = (size_t)row * 256 + (lane & 3) * 8;
    }
    size_t boff[4];
#pragma unroll
    for (int ni = 0; ni < 4; ni++)
        boff[ni] = (size_t)(bcol + ni * 16 + r15) * 256 + g * 8;

    f32x4 acc[2][4];
#pragma unroll
    for (int mi = 0; mi < 2; mi++)
#pragma unroll
        for (int ni = 0; ni < 4; ni++) acc[mi][ni] = (f32x4){0.f, 0.f, 0.f, 0.f};

    uint4 Ar0[4], Ar1[4];     // [h0,h1,l0,l1]
    uint4 Bs0[4], Bs1[4];

    auto loadA = [&](int t, uint4 (&d)[4]) {
        d[0] = *(const uint4*)&Ahg[aoff[0] + t * 32];
        d[1] = *(const uint4*)&Ahg[aoff[1] + t * 32];
        d[2] = *(const uint4*)&Alg[aoff[0] + t * 32];
        d[3] = *(const uint4*)&Alg[aoff[1] + t * 32];
    };
    auto loadB = [&](int t, uint4 (&d)[4]) {
#pragma unroll
        for (int ni = 0; ni < 4; ni++) d[ni] = *(const uint4*)&Bg[boff[ni] + t * 32];
    };
    auto writeA = [&](const uint4 (&s)[4], int buf) {
#pragma unroll
        for (int i = 0; i < 2; i++) {
            int row2 = (lane >> 2) + 16 * i;
            int idx = lbase + buf * 2 * 1280 + row2 * 40 + (lane & 3) * 8;
            *(uint4*)&lds[idx] = s[i];
            *(uint4*)&lds[idx + 1280] = s[2 + i];
        }
    };
    auto compute = [&](int buf, const uint4 (&Bv)[4]) {
        bf16x8 afh[2], afl[2];
#pragma unroll
        for (int mi = 0; mi < 2; mi++) {
            int row = mi * 16 + r15;
            int idx = lbase + buf * 2 * 1280 + row * 40 + g * 8;
            afh[mi] = *(const bf16x8*)&lds[idx];
            afl[mi] = *(const bf16x8*)&lds[idx + 1280];
        }
#pragma unroll
        for (int mi = 0; mi < 2; mi++)
#pragma unroll
            for (int ni = 0; ni < 4; ni++) {
                bf16x8 bb = __builtin_bit_cast(bf16x8, Bv[ni]);
                acc[mi][ni] = __builtin_amdgcn_mfma_f32_16x16x32_bf16(afh[mi], bb, acc[mi][ni], 0, 0, 0);
                acc[mi][ni] = __builtin_amdgcn_mfma_f32_16x16x32_bf16(afl[mi], bb, acc[mi][ni], 0, 0, 0);
            }
    };

    // prologue; NT = 8
    loadA(0, Ar0); loadB(0, Bs0);
    writeA(Ar0, 0);
    loadA(1, Ar1); loadB(1, Bs1);
    for (int tt = 0; tt < 3; ++tt) {            // t = 0..5
        int t0 = 2 * tt;
        loadA(t0 + 2, Ar0);
        compute(0, Bs0);
        loadB(t0 + 2, Bs0);
        writeA(Ar1, 1);
        loadA(t0 + 3, Ar1);
        compute(1, Bs1);
        loadB(t0 + 3, Bs1);
        writeA(Ar0, 0);
    }
    compute(0, Bs0);     // t=6
    writeA(Ar1, 1);      // tile 7
    compute(1, Bs1);     // t=7

#pragma unroll
    for (int mi = 0; mi < 2; mi++) {
#pragma unroll
        for (int ni = 0; ni < 4; ni++) {
            int col = bcol + ni * 16 + r15;
            float bsv = bias[col & (HD - 1)];
            int rbase = wrow + mi * 16 + g * 4;
#pragma unroll
            for (int r = 0; r < 4; r++) {
                int grow = rbase + r;
                if (grow >= M) continue;
                float v = acc[mi][ni][r] + bsv;
                if (MODE == 1) {
                    v = v > 0.f ? v : 0.01f * v;   // lrelu
                    u16 h, l; split_tr(v, h, l);
                    O1h[(size_t)grow * HD + col] = h;
                    O1l[(size_t)grow * HD + col] = l;
                } else {
                    v = fmaxf(v, 0.f);             // relu
                    if (col < 2 * HD) {
                        O1h[((size_t)(col >> 8) * NN + grow) * HD + (col & (HD - 1))] = f2bf_rne(v);
                    } else {
                        O2[(size_t)grow * HD + (col & (HD - 1))] = v;
                    }
                }
            }
        }
    }
}

// ---- weight RNE-round+transpose: W f32 [K][Ncol] -> T bf16 [colOff+n][K] ----
__global__ void conv_w(const float* __restrict__ W, int K, int Ncol,
                       u16* __restrict__ Th, int colOff)
{
    int i = blockIdx.x * 256 + threadIdx.x;
    if (i >= K * Ncol) return;
    int k = i / Ncol, n = i % Ncol;
    Th[(size_t)(colOff + n) * K + k] = f2bf_rne(W[i]);
}

// ---------------- small f32 GEMM (K=5/3), bf16-pair out ----------------
template<int BM, int BN, int BK, int TM, int TN>
__global__ __launch_bounds__(256) void gemm_f32s(
    const float* __restrict__ A, int lda,
    const float* __restrict__ B, int ldb,
    const float* __restrict__ bias,
    u16* __restrict__ Ch, u16* __restrict__ Cl, int coff,
    int M, int Ncol, int K)
{
    constexpr int TX = BN / TN;
    __shared__ float As[BK][BM + 4];
    __shared__ float Bs[BK][BN + 4];
    const int tid = threadIdx.x;
    const int tx = tid % TX, ty = tid / TX;
    const int brow = blockIdx.y * BM;
    const int bcol = blockIdx.x * BN;
    float acc[TM][TN];
#pragma unroll
    for (int i = 0; i < TM; i++)
#pragma unroll
        for (int j = 0; j < TN; j++) acc[i][j] = 0.f;
    for (int k0 = 0; k0 < K; k0 += BK) {
#pragma unroll
        for (int idx = tid; idx < BM * BK; idx += 256) {
            int m = idx / BK, k = idx % BK;
            int gr = brow + m, gk = k0 + k;
            As[k][m] = (gr < M && gk < K) ? A[(size_t)gr * lda + gk] : 0.f;
        }
#pragma unroll
        for (int idx = tid; idx < BK * BN; idx += 256) {
            int k = idx / BN, n = idx % BN;
            int gk = k0 + k, gc = bcol + n;
            Bs[k][n] = (gk < K && gc < Ncol) ? B[(size_t)gk * ldb + gc] : 0.f;
        }
        __syncthreads();
#pragma unroll
        for (int k = 0; k < BK; k++) {
            float a[TM], b[TN];
#pragma unroll
            for (int i = 0; i < TM; i++) a[i] = As[k][ty * TM + i];
#pragma unroll
            for (int j = 0; j < TN; j++) b[j] = Bs[k][tx * TN + j];
#pragma unroll
            for (int i = 0; i < TM; i++)
#pragma unroll
                for (int j = 0; j < TN; j++) acc[i][j] = fmaf(a[i], b[j], acc[i][j]);
        }
        __syncthreads();
    }
#pragma unroll
    for (int i = 0; i < TM; i++) {
        int gr = brow + ty * TM + i;
        if (gr >= M) continue;
#pragma unroll
        for (int j = 0; j < TN; j++) {
            int gc = bcol + tx * TN + j;
            if (gc >= Ncol) continue;
            float v = acc[i][j] + bias[gc];
            v = v > 0.f ? v : 0.01f * v;
            u16 h, l; split_tr(v, h, l);
            Ch[(size_t)gr * HD + coff + gc] = h;
            Cl[(size_t)gr * HD + coff + gc] = l;
        }
    }
}

// ---------------- CSR build ----------------
__global__ void count_seg(const int* __restrict__ ei, const int* __restrict__ et,
                          int* __restrict__ segc)
{
    int e = blockIdx.x * blockDim.x + threadIdx.x;
    if (e < EE) {
        int dst = ei[EE + e];
        int r = et[e];
        atomicAdd(&segc[r * NN + dst], 1);
    }
}

__global__ __launch_bounds__(256) void scan_local(const int* __restrict__ segc,
                                                  int* __restrict__ offs,
                                                  int* __restrict__ bsum)
{
    int b = blockIdx.x;
    int base = b * CHUNK;
    int tid = threadIdx.x;
    int lane = tid & 63, wave = tid >> 6;
    __shared__ int wsum[4];
    int vals[8];
    int i0 = base + tid * 8;
    int s = 0;
    if (i0 + 7 < NSEG) {
        int4 v0 = *(const int4*)&segc[i0];
        int4 v1 = *(const int4*)&segc[i0 + 4];
        vals[0] = v0.x; vals[1] = v0.y; vals[2] = v0.z; vals[3] = v0.w;
        vals[4] = v1.x; vals[5] = v1.y; vals[6] = v1.z; vals[7] = v1.w;
    } else {
#pragma unroll
        for (int j = 0; j < 8; j++) vals[j] = (i0 + j < NSEG) ? segc[i0 + j] : 0;
    }
#pragma unroll
    for (int j = 0; j < 8; j++) s += vals[j];
    int v = s;
#pragma unroll
    for (int off = 1; off < 64; off <<= 1) {
        int u = __shfl_up(v, off);
        if (lane >= off) v += u;
    }
    if (lane == 63) wsum[wave] = v;
    __syncthreads();
    int wbase = 0;
#pragma unroll
    for (int ww = 0; ww < 4; ww++) if (ww < wave) wbase += wsum[ww];
    int run = wbase + v - s;
#pragma unroll
    for (int j = 0; j < 8; j++) {
        run += vals[j];
        int i = i0 + j;
        if (i < NSEG) offs[i + 1] = run;
    }
    if (tid == 0) {
        int t = 0;
#pragma unroll
        for (int ww = 0; ww < 4; ww++) t += wsum[ww];
        bsum[b] = t;
    }
}

__global__ void scan_bsum(const int* __restrict__ bsum, int* __restrict__ bbase)
{
    int lane = threadIdx.x;
    int c = (lane < NB) ? bsum[lane] : 0;
    int v = c;
#pragma unroll
    for (int off = 1; off < 64; off <<= 1) {
        int u = __shfl_up(v, off);
        if (lane >= off) v += u;
    }
    if (lane < NB) bbase[lane] = v - c;
}

__global__ void add_base(int* __restrict__ offs, const int* __restrict__ bbase)
{
    int i = blockIdx.x * blockDim.x + threadIdx.x;
    if (i < NSEG) offs[i + 1] += bbase[i / CHUNK];
    if (i == 0) offs[0] = 0;
}

__global__ void fill_src(const int* __restrict__ ei, const int* __restrict__ et,
                         const int* __restrict__ offs, int* __restrict__ cursor,
                         int* __restrict__ src_list)
{
    int e = blockIdx.x * blockDim.x + threadIdx.x;
    if (e < EE) {
        int src = ei[e];
        int dst = ei[EE + e];
        int s = et[e] * NN + dst;
        int pos = offs[s] + atomicAdd(&cursor[s], 1);
        src_list[pos] = src;
    }
}

// ---------------- gather: v = base + sum_r mean(hrel_bf16) ----------------
// OUTM 0: write bf16 hi/lo pair (next layer input).
// OUTM 1: fused head: logits[d,c] = v . w_out[:,c] + b_out[c]
template<int OUTM>
__global__ __launch_bounds__(256) void gather_mean_b(
    const u16* __restrict__ hrelb,
    const int* __restrict__ offs,
    const int* __restrict__ src_list,
    const float* __restrict__ basein,
    u16* __restrict__ Oh, u16* __restrict__ Ol,
    const float* __restrict__ wout, const float* __restrict__ bout,
    float* __restrict__ logits)
{
    int d = blockIdx.x * 4 + (threadIdx.x >> 6);
    if (d >= NN) return;
    int lane = threadIdx.x & 63;
    f32x4 acc = {0.f, 0.f, 0.f, 0.f};
#pragma unroll
    for (int r = 0; r < 2; r++) {
        int s = r * NN + d;
        int start = offs[s], end = offs[s + 1];
        if (start == end) continue;
        f32x4 a = {0.f, 0.f, 0.f, 0.f};
        const u16* hb = hrelb + (size_t)r * NN * HD;
        for (int i = start; i < end; i++) {
            int src = src_list[i];
            uint2 wv = *(const uint2*)(hb + (size_t)src * HD + lane * 4);
            a.x += __uint_as_float(wv.x << 16);
            a.y += __uint_as_float(wv.x & 0xFFFF0000u);
            a.z += __uint_as_float(wv.y << 16);
            a.w += __uint_as_float(wv.y & 0xFFFF0000u);
        }
        float inv = 1.0f / (float)(end - start);
        acc.x += a.x * inv; acc.y += a.y * inv;
        acc.z += a.z * inv; acc.w += a.w * inv;
    }
    float4 b = ((const float4*)(basein + (size_t)d * HD))[lane];
    float v0 = b.x + acc.x, v1 = b.y + acc.y, v2 = b.z + acc.z, v3 = b.w + acc.w;
    if (OUTM == 0) {
        u16 h0, l0, h1, l1, h2, l2, h3, l3;
        split_tr(v0, h0, l0); split_tr(v1, h1, l1);
        split_tr(v2, h2, l2); split_tr(v3, h3, l3);
        uint2 uh, ul;
        uh.x = (unsigned)h0 | ((unsigned)h1 << 16);
        uh.y = (unsigned)h2 | ((unsigned)h3 << 16);
        ul.x = (unsigned)l0 | ((unsigned)l1 << 16);
        ul.y = (unsigned)l2 | ((unsigned)l3 << 16);
        *(uint2*)(Oh + (size_t)d * HD + lane * 4) = uh;
        *(uint2*)(Ol + (size_t)d * HD + lane * 4) = ul;
    } else {
        int k = lane * 4;
        float a0 = v0 * wout[(k + 0) * 2 + 0] + v1 * wout[(k + 1) * 2 + 0]
                 + v2 * wout[(k + 2) * 2 + 0] + v3 * wout[(k + 3) * 2 + 0];
        float a1 = v0 * wout[(k + 0) * 2 + 1] + v1 * wout[(k + 1) * 2 + 1]
                 + v2 * wout[(k + 2) * 2 + 1] + v3 * wout[(k + 3) * 2 + 1];
#pragma unroll
        for (int off = 32; off > 0; off >>= 1) {
            a0 += __shfl_down(a0, off);
            a1 += __shfl_down(a1, off);
        }
        if (lane == 0) {
            logits[(size_t)d * 2 + 0] = a0 + bout[0];
            logits[(size_t)d * 2 + 1] = a1 + bout[1];
        }
    }
}

extern "C" void kernel_launch(void* const* d_in, const int* in_sizes, int n_in,
                              void* d_out, int out_size, void* d_ws, size_t ws_size,
                              hipStream_t stream)
{
    const float* des   = (const float*)d_in[0];
    const float* tweet = (const float*)d_in[1];
    const float* nump  = (const float*)d_in[2];
    const float* catp  = (const float*)d_in[3];
    const int*   ei    = (const int*)d_in[4];
    const int*   et    = (const int*)d_in[5];
    const float* w_des = (const float*)d_in[6],  *b_des = (const float*)d_in[7];
    const float* w_tw  = (const float*)d_in[8],  *b_tw  = (const float*)d_in[9];
    const float* w_num = (const float*)d_in[10], *b_num = (const float*)d_in[11];
    const float* w_cat = (const float*)d_in[12], *b_cat = (const float*)d_in[13];
    const float* w_in  = (const float*)d_in[14], *b_in  = (const float*)d_in[15];
    const float* weight1 = (const float*)d_in[16], *root1 = (const float*)d_in[17], *bias1 = (const float*)d_in[18];
    const float* weight2 = (const float*)d_in[19], *root2 = (const float*)d_in[20], *bias2 = (const float*)d_in[21];
    const float* w_out = (const float*)d_in[22], *b_out = (const float*)d_in[23];
    float* outp = (float*)d_out;

    const int HSZ = HD * HD, PSZ = 768 * 64;

    // ---- workspace carve-up ----
    float* base  = (float*)d_ws;                       // [N,HD] f32
    u16*   hrelb = (u16*)(base + (size_t)NN * HD);     // [2,N,HD] bf16
    u16*   xh    = hrelb + (size_t)2 * NN * HD;
    u16*   xl    = xh + (size_t)NN * HD;
    u16*   yh    = xl + (size_t)NN * HD;
    u16*   yl    = yh + (size_t)NN * HD;
    int*   offs  = (int*)(yl + (size_t)NN * HD);
    int*   segc  = offs + (NSEG + 1);
    int*   srcl  = segc + NSEG;
    int*   bsum  = srcl + EE;
    int*   bbase = bsum + NB;
    uintptr_t wp = ((uintptr_t)(bbase + NB) + 15) & ~(uintptr_t)15;
    u16* desB = (u16*)wp;
    u16* twB  = desB + PSZ;
    u16* winB = twB + PSZ;
    u16* cat1 = winB + HSZ;
    u16* cat2 = cat1 + 3 * HSZ;

    // ---- CSR build ----
    hipMemsetAsync(segc, 0, NSEG * sizeof(int), stream);
    count_seg<<<(EE + 255) / 256, 256, 0, stream>>>(ei, et, segc);
    scan_local<<<NB, 256, 0, stream>>>(segc, offs, bsum);
    scan_bsum<<<1, 64, 0, stream>>>(bsum, bbase);
    add_base<<<(NSEG + 255) / 256, 256, 0, stream>>>(offs, bbase);
    hipMemsetAsync(segc, 0, NSEG * sizeof(int), stream);
    fill_src<<<(EE + 255) / 256, 256, 0, stream>>>(ei, et, offs, segc, srcl);

    // ---- weight RNE+transpose ----
    conv_w<<<(PSZ + 255) / 256, 256, 0, stream>>>(w_des, 768, 64, desB, 0);
    conv_w<<<(PSZ + 255) / 256, 256, 0, stream>>>(w_tw,  768, 64, twB,  0);
    conv_w<<<(HSZ + 255) / 256, 256, 0, stream>>>(w_in, HD, HD, winB, 0);
    conv_w<<<(HSZ + 255) / 256, 256, 0, stream>>>(weight1,       HD, HD, cat1, 0);
    conv_w<<<(HSZ + 255) / 256, 256, 0, stream>>>(weight1 + HSZ, HD, HD, cat1, 256);
    conv_w<<<(HSZ + 255) / 256, 256, 0, stream>>>(root1,         HD, HD, cat1, 512);
    conv_w<<<(HSZ + 255) / 256, 256, 0, stream>>>(weight2,       HD, HD, cat2, 0);
    conv_w<<<(HSZ + 255) / 256, 256, 0, stream>>>(weight2 + HSZ, HD, HD, cat2, 256);
    conv_w<<<(HSZ + 255) / 256, 256, 0, stream>>>(root2,         HD, HD, cat2, 512);

    const int NYB = (NN + 127) / 128;    // 391 (128-row blocks)

    // ---- fused feature projections (des+tweet) -> xh/xl ----
    gemm_projW<<<2 * NYB, 256, 0, stream>>>(des, tweet, desB, twB, b_des, b_tw, xh, xl);
    dim3 gsmall(1, (NN + 63) / 64);
    gemm_f32s<64, 64, 8, 4, 4><<<gsmall, 256, 0, stream>>>(nump, 5, w_num, 64, b_num, xh, xl, 128, NN, 64, 5);
    gemm_f32s<64, 64, 8, 4, 4><<<gsmall, 256, 0, stream>>>(catp, 3, w_cat, 64, b_cat, xh, xl, 192, NN, 64, 3);

    // ---- y = lrelu(x @ w_in + b_in) -> yh/yl ----
    gemm_waveB<1><<<4 * NYB, 256, 0, stream>>>(xh, xl, winB, b_in, yh, yl, nullptr, NN, 4);

    // ---- layer 1: fused [W_r0|W_r1|root1] -> hrelb (bf16) + base (f32) ----
    gemm_waveB<2><<<12 * NYB, 256, 0, stream>>>(yh, yl, cat1, bias1, hrelb, nullptr, base, NN, 12);
    gather_mean_b<0><<<(NN + 3) / 4, 256, 0, stream>>>(hrelb, offs, srcl, base, xh, xl, nullptr, nullptr, nullptr);

    // ---- layer 2 + fused output head ----
    gemm_waveB<2><<<12 * NYB, 256, 0, stream>>>(xh, xl, cat2, bias2, hrelb, nullptr, base, NN, 12);
    gather_mean_b<1><<<(NN + 3) / 4, 256, 0, stream>>>(hrelb, offs, srcl, base, nullptr, nullptr, w_out, b_out, outp);
}

// Round 13
// 622.806 us; speedup vs baseline: 1.6307x; 1.6307x over previous
//
#include <hip/hip_runtime.h>

#define NN 50000
#define EE 800000
#define HD 256
#define NSEG (2 * NN)
#define CHUNK 2048
#define NB ((NSEG + CHUNK - 1) / CHUNK)

typedef unsigned short u16;
typedef unsigned long long u64;
typedef short bf16x8 __attribute__((ext_vector_type(8)));
typedef float f32x4 __attribute__((ext_vector_type(4)));

__device__ __forceinline__ u16 f2bf_rne(float f) {
    unsigned u = __float_as_uint(f);
    return (u16)((u + 0x7FFF + ((u >> 16) & 1)) >> 16);
}
// trunc hi + RNE residual: (h,l) represents v to ~2^-17 relative
__device__ __forceinline__ void split_tr(float v, u16& h, u16& l) {
    unsigned u = __float_as_uint(v);
    h = (u16)(u >> 16);
    l = f2bf_rne(v - __uint_as_float(u & 0xFFFF0000u));
}

// bijective XCD-chunked swizzle (m204)
__device__ __forceinline__ int xcd_swizzle(int orig, int nwg) {
    int q = nwg >> 3, r = nwg & 7;
    int xcd = orig & 7, idx = orig >> 3;
    return (xcd < r ? xcd * (q + 1) : r * (q + 1) + (xcd - r) * q) + idx;
}

// async global->LDS, 16B per lane; LDS dest = wave-uniform base + lane*16
__device__ __forceinline__ void g2l16(const void* g, void* l) {
    __builtin_amdgcn_global_load_lds(
        (const __attribute__((address_space(1))) void*)g,
        (__attribute__((address_space(3))) void*)l, 16, 0, 0);
}

// bank swizzle for 64B-row bf16 tiles
__device__ __forceinline__ int swz2(int row) { return (row & 2) | ((row >> 2) & 1); }

// stage one 128x32 bf16 tile from G[rc][K] (k-contiguous), source-swizzled
__device__ __forceinline__ void stage_bf16(const u16* __restrict__ G, u16* S,
                                           int base_rc, int maxrc, int K, int k0, int tid) {
#pragma unroll
    for (int s = 0; s < 2; s++) {
        int slot = tid + s * 256;
        int row = slot >> 2, gg = slot & 3;
        int gsrc = gg ^ swz2(row);
        int arow = base_rc + row; arow = arow < maxrc ? arow : maxrc - 1;
        g2l16(G + (size_t)arow * K + k0 + gsrc * 8, S + ((tid & ~63) + s * 256) * 8);
    }
}

// ============ counted-vmcnt dbuf bf16 GEMM (round-10 proven): A hi/lo pair, B bf16 ====
// acc = Ah*Bh + Al*Bh. BM=BN=128, 4 waves 2x2, MFMA 16x16x32, k-map k=k0+g*8+j.
// Stage = 6 VMEM/thread -> steady-state wait vmcnt(6) keeps next tile in flight.
// MODE 1: lrelu -> bf16 pair out (w_in). MODE 2: relu; col<512 -> bf16 hrel; else f32 O2.
template<int MODE>
__global__ __launch_bounds__(256) void gemm_bf16L(
    const u16* __restrict__ Ahg, const u16* __restrict__ Alg,
    const u16* __restrict__ Bhg,
    const float* __restrict__ bias,
    u16* __restrict__ O1h, u16* __restrict__ O1l, float* __restrict__ O2,
    int M, int nxb)
{
    __shared__ __align__(16) u16 sAh[2][128 * 32];
    __shared__ __align__(16) u16 sAl[2][128 * 32];
    __shared__ __align__(16) u16 sBh[2][128 * 32];
    const int wgid = xcd_swizzle(blockIdx.x, gridDim.x);
    const int brow = (wgid / nxb) * 128, bcol = (wgid % nxb) * 128;
    const int tid = threadIdx.x, lane = tid & 63, w = tid >> 6;
    const int wr = w >> 1, wc = w & 1;
    const int r15 = lane & 15, g = lane >> 4;
    const int fsw = (g ^ swz2(r15)) * 8;

    f32x4 acc[4][4];
#pragma unroll
    for (int mi = 0; mi < 4; mi++)
#pragma unroll
        for (int ni = 0; ni < 4; ni++) acc[mi][ni] = (f32x4){0.f, 0.f, 0.f, 0.f};

    auto stage_step = [&](int k0, int b) {       // 6 VMEM instr per thread
        stage_bf16(Ahg, sAh[b], brow, M, 256, k0, tid);
        stage_bf16(Alg, sAl[b], brow, M, 256, k0, tid);
        stage_bf16(Bhg, sBh[b], bcol, 1 << 30, 256, k0, tid);
    };
    auto compute_step = [&](int b) {
        bf16x8 afh[4], afl[4], bfh[4];
#pragma unroll
        for (int mi = 0; mi < 4; mi++) {
            int idx = (wr * 64 + mi * 16 + r15) * 32 + fsw;
            afh[mi] = *(const bf16x8*)&sAh[b][idx];
            afl[mi] = *(const bf16x8*)&sAl[b][idx];
        }
#pragma unroll
        for (int ni = 0; ni < 4; ni++) {
            int idx = (wc * 64 + ni * 16 + r15) * 32 + fsw;
            bfh[ni] = *(const bf16x8*)&sBh[b][idx];
        }
#pragma unroll
        for (int mi = 0; mi < 4; mi++)
#pragma unroll
            for (int ni = 0; ni < 4; ni++)
                acc[mi][ni] = __builtin_amdgcn_mfma_f32_16x16x32_bf16(afh[mi], bfh[ni], acc[mi][ni], 0, 0, 0);
#pragma unroll
        for (int mi = 0; mi < 4; mi++)
#pragma unroll
            for (int ni = 0; ni < 4; ni++)
                acc[mi][ni] = __builtin_amdgcn_mfma_f32_16x16x32_bf16(afl[mi], bfh[ni], acc[mi][ni], 0, 0, 0);
    };

    stage_step(0, 0);
    stage_step(32, 1);
#pragma unroll
    for (int t = 0; t < 7; t++) {
        asm volatile("s_waitcnt vmcnt(6)" ::: "memory");   // drain buf[t&1] only
        __builtin_amdgcn_s_barrier();
        compute_step(t & 1);
        __builtin_amdgcn_s_barrier();
        if (t + 2 < 8) stage_step((t + 2) * 32, t & 1);
    }
    asm volatile("s_waitcnt vmcnt(0)" ::: "memory");
    __builtin_amdgcn_s_barrier();
    compute_step(1);

#pragma unroll
    for (int mi = 0; mi < 4; mi++) {
#pragma unroll
        for (int ni = 0; ni < 4; ni++) {
            int col = bcol + wc * 64 + ni * 16 + r15;
            float bsv = bias[col & (HD - 1)];
            int rbase = brow + wr * 64 + mi * 16 + g * 4;
#pragma unroll
            for (int r = 0; r < 4; r++) {
                int grow = rbase + r;
                if (grow >= M) continue;
                float v = acc[mi][ni][r] + bsv;
                if (MODE == 1) {
                    v = v > 0.f ? v : 0.01f * v;   // lrelu
                    u16 h, l; split_tr(v, h, l);
                    O1h[(size_t)grow * HD + col] = h;
                    O1l[(size_t)grow * HD + col] = l;
                } else {
                    v = fmaxf(v, 0.f);             // relu
                    if (col < 2 * HD) {
                        O1h[((size_t)(col >> 8) * NN + grow) * HD + (col & (HD - 1))] = f2bf_rne(v);
                    } else {
                        O2[(size_t)grow * HD + (col & (HD - 1))] = v;
                    }
                }
            }
        }
    }
}

// ===================== wave-autonomous dual-projection GEMM (K=768) =====================
// No barriers (verified math, round 12). Each wave: 32 rows x 64 cols. A f32 coalesced->
// regs->perm-convert->private LDS (dbuf, pad 40); B fragments per-lane direct (L2-hot).
// NEW: epilogue transposes through wave-private LDS -> fully coalesced 16B/lane stores.
__global__ __launch_bounds__(256) void gemm_projW(
    const float* __restrict__ A0, const float* __restrict__ A1,
    const u16* __restrict__ B0, const u16* __restrict__ B1,
    const float* __restrict__ bias0, const float* __restrict__ bias1,
    u16* __restrict__ Ch, u16* __restrict__ Cl)
{
    __shared__ __align__(16) u16 lds[4 * 2 * 2 * 1280];   // [wave][buf][h/l][32*40]
    const int p = blockIdx.x & 1;
    const float* __restrict__ A = p ? A1 : A0;
    const u16* __restrict__ Bp = p ? B1 : B0;
    const float* __restrict__ bias = p ? bias1 : bias0;
    const int coff = p * 64;
    const int tid = threadIdx.x, lane = tid & 63, w = tid >> 6;
    const int wrow = (blockIdx.x >> 1) * 128 + w * 32;
    const int r15 = lane & 15, g = lane >> 4;
    const int lbase = w * 2 * 2 * 1280;

    size_t aoff[4];
#pragma unroll
    for (int i = 0; i < 4; i++) {
        int row = wrow + (lane >> 3) + 8 * i;
        row = row < NN ? row : NN - 1;
        aoff[i] = (size_t)row * 768 + (lane & 7) * 4;
    }
    size_t boff[4];
#pragma unroll
    for (int ni = 0; ni < 4; ni++)
        boff[ni] = (size_t)(ni * 16 + r15) * 768 + g * 8;

    f32x4 acc[2][4];
#pragma unroll
    for (int mi = 0; mi < 2; mi++)
#pragma unroll
        for (int ni = 0; ni < 4; ni++) acc[mi][ni] = (f32x4){0.f, 0.f, 0.f, 0.f};

    float4 Ar0[4], Ar1[4];
    uint4 Bs0[4], Bs1[4];

    auto loadA = [&](int t, float4 (&d)[4]) {
#pragma unroll
        for (int i = 0; i < 4; i++) d[i] = *(const float4*)&A[aoff[i] + t * 32];
    };
    auto loadB = [&](int t, uint4 (&d)[4]) {
#pragma unroll
        for (int ni = 0; ni < 4; ni++) d[ni] = *(const uint4*)&Bp[boff[ni] + t * 32];
    };
    auto writeA = [&](const float4 (&s)[4], int buf) {
#pragma unroll
        for (int i = 0; i < 4; i++) {
            int row2 = (lane >> 3) + 8 * i;
            unsigned e0 = __float_as_uint(s[i].x), e1 = __float_as_uint(s[i].y),
                     e2 = __float_as_uint(s[i].z), e3 = __float_as_uint(s[i].w);
            unsigned h0 = __builtin_amdgcn_perm(e1, e0, 0x07060302u);
            unsigned h1 = __builtin_amdgcn_perm(e3, e2, 0x07060302u);
            unsigned q0 = __float_as_uint(s[i].x - __uint_as_float(e0 & 0xFFFF0000u));
            unsigned q1 = __float_as_uint(s[i].y - __uint_as_float(e1 & 0xFFFF0000u));
            unsigned q2 = __float_as_uint(s[i].z - __uint_as_float(e2 & 0xFFFF0000u));
            unsigned q3 = __float_as_uint(s[i].w - __uint_as_float(e3 & 0xFFFF0000u));
            unsigned l0 = __builtin_amdgcn_perm(q1, q0, 0x07060302u);
            unsigned l1 = __builtin_amdgcn_perm(q3, q2, 0x07060302u);
            int idx = lbase + buf * 2 * 1280 + row2 * 40 + (lane & 7) * 4;
            *(u64*)&lds[idx] = (u64)h0 | ((u64)h1 << 32);
            *(u64*)&lds[idx + 1280] = (u64)l0 | ((u64)l1 << 32);
        }
    };
    auto compute = [&](int buf, const uint4 (&Bv)[4]) {
        bf16x8 afh[2], afl[2];
#pragma unroll
        for (int mi = 0; mi < 2; mi++) {
            int row = mi * 16 + r15;
            int idx = lbase + buf * 2 * 1280 + row * 40 + g * 8;
            afh[mi] = *(const bf16x8*)&lds[idx];
            afl[mi] = *(const bf16x8*)&lds[idx + 1280];
        }
#pragma unroll
        for (int mi = 0; mi < 2; mi++)
#pragma unroll
            for (int ni = 0; ni < 4; ni++) {
                bf16x8 bb = __builtin_bit_cast(bf16x8, Bv[ni]);
                acc[mi][ni] = __builtin_amdgcn_mfma_f32_16x16x32_bf16(afh[mi], bb, acc[mi][ni], 0, 0, 0);
                acc[mi][ni] = __builtin_amdgcn_mfma_f32_16x16x32_bf16(afl[mi], bb, acc[mi][ni], 0, 0, 0);
            }
    };

    // prologue
    loadA(0, Ar0); loadB(0, Bs0);
    writeA(Ar0, 0);
    loadA(1, Ar1); loadB(1, Bs1);
    // steady: t = 0..21 (NT=24)
    for (int tt = 0; tt < 11; ++tt) {
        int t0 = 2 * tt;
        loadA(t0 + 2, Ar0);
        compute(0, Bs0);
        loadB(t0 + 2, Bs0);
        writeA(Ar1, 1);
        loadA(t0 + 3, Ar1);
        compute(1, Bs1);
        loadB(t0 + 3, Bs1);
        writeA(Ar0, 0);
    }
    compute(0, Bs0);     // t=22
    writeA(Ar1, 1);      // tile 23 -> buf1
    compute(1, Bs1);     // t=23

    // ---- coalesced epilogue: acc -> wave-private LDS (h & l planes) -> 16B stores ----
    u16* tlh = &lds[w * 5120];      // 32 x 72 u16 (pad 8) per plane
    u16* tll = tlh + 2304;
#pragma unroll
    for (int mi = 0; mi < 2; mi++) {
#pragma unroll
        for (int ni = 0; ni < 4; ni++) {
            int col = ni * 16 + r15;
            float bsv = bias[col];
#pragma unroll
            for (int r = 0; r < 4; r++) {
                int row = mi * 16 + g * 4 + r;
                float v = acc[mi][ni][r] + bsv;
                v = v > 0.f ? v : 0.01f * v;   // lrelu
                u16 h, l; split_tr(v, h, l);
                tlh[row * 72 + col] = h;
                tll[row * 72 + col] = l;
            }
        }
    }
    asm volatile("s_waitcnt lgkmcnt(0)" ::: "memory");
    __builtin_amdgcn_sched_barrier(0);
    {
        int row = lane >> 1, cb = (lane & 1) * 32;
        int grow = wrow + row;
        if (grow < NN) {
#pragma unroll
            for (int j = 0; j < 4; j++) {
                uint4 hv = *(const uint4*)&tlh[row * 72 + cb + j * 8];
                uint4 lv = *(const uint4*)&tll[row * 72 + cb + j * 8];
                *(uint4*)&Ch[(size_t)grow * HD + coff + cb + j * 8] = hv;
                *(uint4*)&Cl[(size_t)grow * HD + coff + cb + j * 8] = lv;
            }
        }
    }
}

// ---- weight RNE-round+transpose: W f32 [K][Ncol] -> T bf16 [colOff+n][K] ----
__global__ void conv_w(const float* __restrict__ W, int K, int Ncol,
                       u16* __restrict__ Th, int colOff)
{
    int i = blockIdx.x * 256 + threadIdx.x;
    if (i >= K * Ncol) return;
    int k = i / Ncol, n = i % Ncol;
    Th[(size_t)(colOff + n) * K + k] = f2bf_rne(W[i]);
}

// ---------------- small f32 GEMM (K=5/3), bf16-pair out ----------------
template<int BM, int BN, int BK, int TM, int TN>
__global__ __launch_bounds__(256) void gemm_f32s(
    const float* __restrict__ A, int lda,
    const float* __restrict__ B, int ldb,
    const float* __restrict__ bias,
    u16* __restrict__ Ch, u16* __restrict__ Cl, int coff,
    int M, int Ncol, int K)
{
    constexpr int TX = BN / TN;
    __shared__ float As[BK][BM + 4];
    __shared__ float Bs[BK][BN + 4];
    const int tid = threadIdx.x;
    const int tx = tid % TX, ty = tid / TX;
    const int brow = blockIdx.y * BM;
    const int bcol = blockIdx.x * BN;
    float acc[TM][TN];
#pragma unroll
    for (int i = 0; i < TM; i++)
#pragma unroll
        for (int j = 0; j < TN; j++) acc[i][j] = 0.f;
    for (int k0 = 0; k0 < K; k0 += BK) {
#pragma unroll
        for (int idx = tid; idx < BM * BK; idx += 256) {
            int m = idx / BK, k = idx % BK;
            int gr = brow + m, gk = k0 + k;
            As[k][m] = (gr < M && gk < K) ? A[(size_t)gr * lda + gk] : 0.f;
        }
#pragma unroll
        for (int idx = tid; idx < BK * BN; idx += 256) {
            int k = idx / BN, n = idx % BN;
            int gk = k0 + k, gc = bcol + n;
            Bs[k][n] = (gk < K && gc < Ncol) ? B[(size_t)gk * ldb + gc] : 0.f;
        }
        __syncthreads();
#pragma unroll
        for (int k = 0; k < BK; k++) {
            float a[TM], b[TN];
#pragma unroll
            for (int i = 0; i < TM; i++) a[i] = As[k][ty * TM + i];
#pragma unroll
            for (int j = 0; j < TN; j++) b[j] = Bs[k][tx * TN + j];
#pragma unroll
            for (int i = 0; i < TM; i++)
#pragma unroll
                for (int j = 0; j < TN; j++) acc[i][j] = fmaf(a[i], b[j], acc[i][j]);
        }
        __syncthreads();
    }
#pragma unroll
    for (int i = 0; i < TM; i++) {
        int gr = brow + ty * TM + i;
        if (gr >= M) continue;
#pragma unroll
        for (int j = 0; j < TN; j++) {
            int gc = bcol + tx * TN + j;
            if (gc >= Ncol) continue;
            float v = acc[i][j] + bias[gc];
            v = v > 0.f ? v : 0.01f * v;
            u16 h, l; split_tr(v, h, l);
            Ch[(size_t)gr * HD + coff + gc] = h;
            Cl[(size_t)gr * HD + coff + gc] = l;
        }
    }
}

// ---------------- CSR build ----------------
__global__ void count_seg(const int* __restrict__ ei, const int* __restrict__ et,
                          int* __restrict__ segc)
{
    int e = blockIdx.x * blockDim.x + threadIdx.x;
    if (e < EE) {
        int dst = ei[EE + e];
        int r = et[e];
        atomicAdd(&segc[r * NN + dst], 1);
    }
}

__global__ __launch_bounds__(256) void scan_local(const int* __restrict__ segc,
                                                  int* __restrict__ offs,
                                                  int* __restrict__ bsum)
{
    int b = blockIdx.x;
    int base = b * CHUNK;
    int tid = threadIdx.x;
    int lane = tid & 63, wave = tid >> 6;
    __shared__ int wsum[4];
    int vals[8];
    int i0 = base + tid * 8;
    int s = 0;
    if (i0 + 7 < NSEG) {
        int4 v0 = *(const int4*)&segc[i0];
        int4 v1 = *(const int4*)&segc[i0 + 4];
        vals[0] = v0.x; vals[1] = v0.y; vals[2] = v0.z; vals[3] = v0.w;
        vals[4] = v1.x; vals[5] = v1.y; vals[6] = v1.z; vals[7] = v1.w;
    } else {
#pragma unroll
        for (int j = 0; j < 8; j++) vals[j] = (i0 + j < NSEG) ? segc[i0 + j] : 0;
    }
#pragma unroll
    for (int j = 0; j < 8; j++) s += vals[j];
    int v = s;
#pragma unroll
    for (int off = 1; off < 64; off <<= 1) {
        int u = __shfl_up(v, off);
        if (lane >= off) v += u;
    }
    if (lane == 63) wsum[wave] = v;
    __syncthreads();
    int wbase = 0;
#pragma unroll
    for (int ww = 0; ww < 4; ww++) if (ww < wave) wbase += wsum[ww];
    int run = wbase + v - s;
#pragma unroll
    for (int j = 0; j < 8; j++) {
        run += vals[j];
        int i = i0 + j;
        if (i < NSEG) offs[i + 1] = run;
    }
    if (tid == 0) {
        int t = 0;
#pragma unroll
        for (int ww = 0; ww < 4; ww++) t += wsum[ww];
        bsum[b] = t;
    }
}

__global__ void scan_bsum(const int* __restrict__ bsum, int* __restrict__ bbase)
{
    int lane = threadIdx.x;
    int c = (lane < NB) ? bsum[lane] : 0;
    int v = c;
#pragma unroll
    for (int off = 1; off < 64; off <<= 1) {
        int u = __shfl_up(v, off);
        if (lane >= off) v += u;
    }
    if (lane < NB) bbase[lane] = v - c;
}

__global__ void add_base(int* __restrict__ offs, const int* __restrict__ bbase)
{
    int i = blockIdx.x * blockDim.x + threadIdx.x;
    if (i < NSEG) offs[i + 1] += bbase[i / CHUNK];
    if (i == 0) offs[0] = 0;
}

__global__ void fill_src(const int* __restrict__ ei, const int* __restrict__ et,
                         const int* __restrict__ offs, int* __restrict__ cursor,
                         int* __restrict__ src_list)
{
    int e = blockIdx.x * blockDim.x + threadIdx.x;
    if (e < EE) {
        int src = ei[e];
        int dst = ei[EE + e];
        int s = et[e] * NN + dst;
        int pos = offs[s] + atomicAdd(&cursor[s], 1);
        src_list[pos] = src;
    }
}

// ---------------- gather: v = base + sum_r mean(hrel_bf16) ----------------
// OUTM 0: write bf16 hi/lo pair (next layer input).
// OUTM 1: fused head: logits[d,c] = v . w_out[:,c] + b_out[c]
template<int OUTM>
__global__ __launch_bounds__(256) void gather_mean_b(
    const u16* __restrict__ hrelb,
    const int* __restrict__ offs,
    const int* __restrict__ src_list,
    const float* __restrict__ basein,
    u16* __restrict__ Oh, u16* __restrict__ Ol,
    const float* __restrict__ wout, const float* __restrict__ bout,
    float* __restrict__ logits)
{
    int d = blockIdx.x * 4 + (threadIdx.x >> 6);
    if (d >= NN) return;
    int lane = threadIdx.x & 63;
    f32x4 acc = {0.f, 0.f, 0.f, 0.f};
#pragma unroll
    for (int r = 0; r < 2; r++) {
        int s = r * NN + d;
        int start = offs[s], end = offs[s + 1];
        if (start == end) continue;
        f32x4 a = {0.f, 0.f, 0.f, 0.f};
        const u16* hb = hrelb + (size_t)r * NN * HD;
        for (int i = start; i < end; i++) {
            int src = src_list[i];
            uint2 wv = *(const uint2*)(hb + (size_t)src * HD + lane * 4);
            a.x += __uint_as_float(wv.x << 16);
            a.y += __uint_as_float(wv.x & 0xFFFF0000u);
            a.z += __uint_as_float(wv.y << 16);
            a.w += __uint_as_float(wv.y & 0xFFFF0000u);
        }
        float inv = 1.0f / (float)(end - start);
        acc.x += a.x * inv; acc.y += a.y * inv;
        acc.z += a.z * inv; acc.w += a.w * inv;
    }
    float4 b = ((const float4*)(basein + (size_t)d * HD))[lane];
    float v0 = b.x + acc.x, v1 = b.y + acc.y, v2 = b.z + acc.z, v3 = b.w + acc.w;
    if (OUTM == 0) {
        u16 h0, l0, h1, l1, h2, l2, h3, l3;
        split_tr(v0, h0, l0); split_tr(v1, h1, l1);
        split_tr(v2, h2, l2); split_tr(v3, h3, l3);
        uint2 uh, ul;
        uh.x = (unsigned)h0 | ((unsigned)h1 << 16);
        uh.y = (unsigned)h2 | ((unsigned)h3 << 16);
        ul.x = (unsigned)l0 | ((unsigned)l1 << 16);
        ul.y = (unsigned)l2 | ((unsigned)l3 << 16);
        *(uint2*)(Oh + (size_t)d * HD + lane * 4) = uh;
        *(uint2*)(Ol + (size_t)d * HD + lane * 4) = ul;
    } else {
        int k = lane * 4;
        float a0 = v0 * wout[(k + 0) * 2 + 0] + v1 * wout[(k + 1) * 2 + 0]
                 + v2 * wout[(k + 2) * 2 + 0] + v3 * wout[(k + 3) * 2 + 0];
        float a1 = v0 * wout[(k + 0) * 2 + 1] + v1 * wout[(k + 1) * 2 + 1]
                 + v2 * wout[(k + 2) * 2 + 1] + v3 * wout[(k + 3) * 2 + 1];
#pragma unroll
        for (int off = 32; off > 0; off >>= 1) {
            a0 += __shfl_down(a0, off);
            a1 += __shfl_down(a1, off);
        }
        if (lane == 0) {
            logits[(size_t)d * 2 + 0] = a0 + bout[0];
            logits[(size_t)d * 2 + 1] = a1 + bout[1];
        }
    }
}

extern "C" void kernel_launch(void* const* d_in, const int* in_sizes, int n_in,
                              void* d_out, int out_size, void* d_ws, size_t ws_size,
                              hipStream_t stream)
{
    const float* des   = (const float*)d_in[0];
    const float* tweet = (const float*)d_in[1];
    const float* nump  = (const float*)d_in[2];
    const float* catp  = (const float*)d_in[3];
    const int*   ei    = (const int*)d_in[4];
    const int*   et    = (const int*)d_in[5];
    const float* w_des = (const float*)d_in[6],  *b_des = (const float*)d_in[7];
    const float* w_tw  = (const float*)d_in[8],  *b_tw  = (const float*)d_in[9];
    const float* w_num = (const float*)d_in[10], *b_num = (const float*)d_in[11];
    const float* w_cat = (const float*)d_in[12], *b_cat = (const float*)d_in[13];
    const float* w_in  = (const float*)d_in[14], *b_in  = (const float*)d_in[15];
    const float* weight1 = (const float*)d_in[16], *root1 = (const float*)d_in[17], *bias1 = (const float*)d_in[18];
    const float* weight2 = (const float*)d_in[19], *root2 = (const float*)d_in[20], *bias2 = (const float*)d_in[21];
    const float* w_out = (const float*)d_in[22], *b_out = (const float*)d_in[23];
    float* outp = (float*)d_out;

    const int HSZ = HD * HD, PSZ = 768 * 64;

    // ---- workspace carve-up ----
    float* base  = (float*)d_ws;                       // [N,HD] f32
    u16*   hrelb = (u16*)(base + (size_t)NN * HD);     // [2,N,HD] bf16
    u16*   xh    = hrelb + (size_t)2 * NN * HD;
    u16*   xl    = xh + (size_t)NN * HD;
    u16*   yh    = xl + (size_t)NN * HD;
    u16*   yl    = yh + (size_t)NN * HD;
    int*   offs  = (int*)(yl + (size_t)NN * HD);
    int*   segc  = offs + (NSEG + 1);
    int*   srcl  = segc + NSEG;
    int*   bsum  = srcl + EE;
    int*   bbase = bsum + NB;
    uintptr_t wp = ((uintptr_t)(bbase + NB) + 15) & ~(uintptr_t)15;
    u16* desB = (u16*)wp;
    u16* twB  = desB + PSZ;
    u16* winB = twB + PSZ;
    u16* cat1 = winB + HSZ;
    u16* cat2 = cat1 + 3 * HSZ;

    // ---- CSR build ----
    hipMemsetAsync(segc, 0, NSEG * sizeof(int), stream);
    count_seg<<<(EE + 255) / 256, 256, 0, stream>>>(ei, et, segc);
    scan_local<<<NB, 256, 0, stream>>>(segc, offs, bsum);
    scan_bsum<<<1, 64, 0, stream>>>(bsum, bbase);
    add_base<<<(NSEG + 255) / 256, 256, 0, stream>>>(offs, bbase);
    hipMemsetAsync(segc, 0, NSEG * sizeof(int), stream);
    fill_src<<<(EE + 255) / 256, 256, 0, stream>>>(ei, et, offs, segc, srcl);

    // ---- weight RNE+transpose ----
    conv_w<<<(PSZ + 255) / 256, 256, 0, stream>>>(w_des, 768, 64, desB, 0);
    conv_w<<<(PSZ + 255) / 256, 256, 0, stream>>>(w_tw,  768, 64, twB,  0);
    conv_w<<<(HSZ + 255) / 256, 256, 0, stream>>>(w_in, HD, HD, winB, 0);
    conv_w<<<(HSZ + 255) / 256, 256, 0, stream>>>(weight1,       HD, HD, cat1, 0);
    conv_w<<<(HSZ + 255) / 256, 256, 0, stream>>>(weight1 + HSZ, HD, HD, cat1, 256);
    conv_w<<<(HSZ + 255) / 256, 256, 0, stream>>>(root1,         HD, HD, cat1, 512);
    conv_w<<<(HSZ + 255) / 256, 256, 0, stream>>>(weight2,       HD, HD, cat2, 0);
    conv_w<<<(HSZ + 255) / 256, 256, 0, stream>>>(weight2 + HSZ, HD, HD, cat2, 256);
    conv_w<<<(HSZ + 255) / 256, 256, 0, stream>>>(root2,         HD, HD, cat2, 512);

    const int NYB = (NN + 127) / 128;    // 391 (128-row blocks)

    // ---- fused feature projections (des+tweet) -> xh/xl (wave-autonomous) ----
    gemm_projW<<<2 * NYB, 256, 0, stream>>>(des, tweet, desB, twB, b_des, b_tw, xh, xl);
    dim3 gsmall(1, (NN + 63) / 64);
    gemm_f32s<64, 64, 8, 4, 4><<<gsmall, 256, 0, stream>>>(nump, 5, w_num, 64, b_num, xh, xl, 128, NN, 64, 5);
    gemm_f32s<64, 64, 8, 4, 4><<<gsmall, 256, 0, stream>>>(catp, 3, w_cat, 64, b_cat, xh, xl, 192, NN, 64, 3);

    // ---- y = lrelu(x @ w_in + b_in) -> yh/yl ----
    gemm_bf16L<1><<<2 * NYB, 256, 0, stream>>>(xh, xl, winB, b_in, yh, yl, nullptr, NN, 2);

    // ---- layer 1: fused [W_r0|W_r1|root1] -> hrelb (bf16) + base (f32) ----
    gemm_bf16L<2><<<6 * NYB, 256, 0, stream>>>(yh, yl, cat1, bias1, hrelb, nullptr, base, NN, 6);
    gather_mean_b<0><<<(NN + 3) / 4, 256, 0, stream>>>(hrelb, offs, srcl, base, xh, xl, nullptr, nullptr, nullptr);

    // ---- layer 2 + fused output head ----
    gemm_bf16L<2><<<6 * NYB, 256, 0, stream>>>(xh, xl, cat2, bias2, hrelb, nullptr, base, NN, 6);
    gather_mean_b<1><<<(NN + 3) / 4, 256, 0, stream>>>(hrelb, offs, srcl, base, nullptr, nullptr, w_out, b_out, outp);
}

// Round 14
// 595.663 us; speedup vs baseline: 1.7050x; 1.0456x over previous
//
#include <hip/hip_runtime.h>

#define NN 50000
#define EE 800000
#define HD 256
#define NSEG (2 * NN)
#define CHUNK 2048
#define NB ((NSEG + CHUNK - 1) / CHUNK)

typedef unsigned short u16;
typedef unsigned long long u64;
typedef short bf16x8 __attribute__((ext_vector_type(8)));
typedef float f32x4 __attribute__((ext_vector_type(4)));

__device__ __forceinline__ u16 f2bf_rne(float f) {
    unsigned u = __float_as_uint(f);
    return (u16)((u + 0x7FFF + ((u >> 16) & 1)) >> 16);
}
// trunc hi + RNE residual: (h,l) represents v to ~2^-17 relative
__device__ __forceinline__ void split_tr(float v, u16& h, u16& l) {
    unsigned u = __float_as_uint(v);
    h = (u16)(u >> 16);
    l = f2bf_rne(v - __uint_as_float(u & 0xFFFF0000u));
}

// bijective XCD-chunked swizzle (m204)
__device__ __forceinline__ int xcd_swizzle(int orig, int nwg) {
    int q = nwg >> 3, r = nwg & 7;
    int xcd = orig & 7, idx = orig >> 3;
    return (xcd < r ? xcd * (q + 1) : r * (q + 1) + (xcd - r) * q) + idx;
}

// async global->LDS, 16B per lane; LDS dest = wave-uniform base + lane*16
__device__ __forceinline__ void g2l16(const void* g, void* l) {
    __builtin_amdgcn_global_load_lds(
        (const __attribute__((address_space(1))) void*)g,
        (__attribute__((address_space(3))) void*)l, 16, 0, 0);
}

// bank swizzle for 64B-row bf16 tiles
__device__ __forceinline__ int swz2(int row) { return (row & 2) | ((row >> 2) & 1); }

// stage one 128x32 bf16 tile from G[rc][K] (k-contiguous), source-swizzled
__device__ __forceinline__ void stage_bf16(const u16* __restrict__ G, u16* S,
                                           int base_rc, int maxrc, int K, int k0, int tid) {
#pragma unroll
    for (int s = 0; s < 2; s++) {
        int slot = tid + s * 256;
        int row = slot >> 2, gg = slot & 3;
        int gsrc = gg ^ swz2(row);
        int arow = base_rc + row; arow = arow < maxrc ? arow : maxrc - 1;
        g2l16(G + (size_t)arow * K + k0 + gsrc * 8, S + ((tid & ~63) + s * 256) * 8);
    }
}

// ============ counted-vmcnt dbuf bf16 GEMM (round-10 proven): A hi/lo pair, B bf16 ====
// acc = Ah*Bh + Al*Bh. BM=BN=128, 4 waves 2x2, MFMA 16x16x32, k-map k=k0+g*8+j.
// MODE 1: lrelu -> bf16 pair out (w_in). MODE 2: relu; col<512 -> bf16 hrel; else f32 O2.
template<int MODE>
__global__ __launch_bounds__(256) void gemm_bf16L(
    const u16* __restrict__ Ahg, const u16* __restrict__ Alg,
    const u16* __restrict__ Bhg,
    const float* __restrict__ bias,
    u16* __restrict__ O1h, u16* __restrict__ O1l, float* __restrict__ O2,
    int M, int nxb)
{
    __shared__ __align__(16) u16 sAh[2][128 * 32];
    __shared__ __align__(16) u16 sAl[2][128 * 32];
    __shared__ __align__(16) u16 sBh[2][128 * 32];
    const int wgid = xcd_swizzle(blockIdx.x, gridDim.x);
    const int brow = (wgid / nxb) * 128, bcol = (wgid % nxb) * 128;
    const int tid = threadIdx.x, lane = tid & 63, w = tid >> 6;
    const int wr = w >> 1, wc = w & 1;
    const int r15 = lane & 15, g = lane >> 4;
    const int fsw = (g ^ swz2(r15)) * 8;

    f32x4 acc[4][4];
#pragma unroll
    for (int mi = 0; mi < 4; mi++)
#pragma unroll
        for (int ni = 0; ni < 4; ni++) acc[mi][ni] = (f32x4){0.f, 0.f, 0.f, 0.f};

    auto stage_step = [&](int k0, int b) {       // 6 VMEM instr per thread
        stage_bf16(Ahg, sAh[b], brow, M, 256, k0, tid);
        stage_bf16(Alg, sAl[b], brow, M, 256, k0, tid);
        stage_bf16(Bhg, sBh[b], bcol, 1 << 30, 256, k0, tid);
    };
    auto compute_step = [&](int b) {
        bf16x8 afh[4], afl[4], bfh[4];
#pragma unroll
        for (int mi = 0; mi < 4; mi++) {
            int idx = (wr * 64 + mi * 16 + r15) * 32 + fsw;
            afh[mi] = *(const bf16x8*)&sAh[b][idx];
            afl[mi] = *(const bf16x8*)&sAl[b][idx];
        }
#pragma unroll
        for (int ni = 0; ni < 4; ni++) {
            int idx = (wc * 64 + ni * 16 + r15) * 32 + fsw;
            bfh[ni] = *(const bf16x8*)&sBh[b][idx];
        }
#pragma unroll
        for (int mi = 0; mi < 4; mi++)
#pragma unroll
            for (int ni = 0; ni < 4; ni++)
                acc[mi][ni] = __builtin_amdgcn_mfma_f32_16x16x32_bf16(afh[mi], bfh[ni], acc[mi][ni], 0, 0, 0);
#pragma unroll
        for (int mi = 0; mi < 4; mi++)
#pragma unroll
            for (int ni = 0; ni < 4; ni++)
                acc[mi][ni] = __builtin_amdgcn_mfma_f32_16x16x32_bf16(afl[mi], bfh[ni], acc[mi][ni], 0, 0, 0);
    };

    stage_step(0, 0);
    stage_step(32, 1);
#pragma unroll
    for (int t = 0; t < 7; t++) {
        asm volatile("s_waitcnt vmcnt(6)" ::: "memory");   // drain buf[t&1] only
        __builtin_amdgcn_s_barrier();
        compute_step(t & 1);
        __builtin_amdgcn_s_barrier();
        if (t + 2 < 8) stage_step((t + 2) * 32, t & 1);
    }
    asm volatile("s_waitcnt vmcnt(0)" ::: "memory");
    __builtin_amdgcn_s_barrier();
    compute_step(1);

#pragma unroll
    for (int mi = 0; mi < 4; mi++) {
#pragma unroll
        for (int ni = 0; ni < 4; ni++) {
            int col = bcol + wc * 64 + ni * 16 + r15;
            float bsv = bias[col & (HD - 1)];
            int rbase = brow + wr * 64 + mi * 16 + g * 4;
#pragma unroll
            for (int r = 0; r < 4; r++) {
                int grow = rbase + r;
                if (grow >= M) continue;
                float v = acc[mi][ni][r] + bsv;
                if (MODE == 1) {
                    v = v > 0.f ? v : 0.01f * v;   // lrelu
                    u16 h, l; split_tr(v, h, l);
                    O1h[(size_t)grow * HD + col] = h;
                    O1l[(size_t)grow * HD + col] = l;
                } else {
                    v = fmaxf(v, 0.f);             // relu
                    if (col < 2 * HD) {
                        O1h[((size_t)(col >> 8) * NN + grow) * HD + (col & (HD - 1))] = f2bf_rne(v);
                    } else {
                        O2[(size_t)grow * HD + (col & (HD - 1))] = v;
                    }
                }
            }
        }
    }
}

// ===================== wave-autonomous dual-projection GEMM (K=768) =====================
// 64-thread blocks (1 wave, 32 rows x 64 cols), no barriers. A f32 coalesced->regs->
// perm-convert->private LDS (dbuf, pad 40). B in FRAGMENT-MAJOR layout: per (t,ni) one
// fully-coalesced 1KB wave load. Coalesced LDS-transpose epilogue. lrelu, bf16-pair out.
__global__ __launch_bounds__(64) void gemm_projW(
    const float* __restrict__ A0, const float* __restrict__ A1,
    const u16* __restrict__ B0, const u16* __restrict__ B1,
    const float* __restrict__ bias0, const float* __restrict__ bias1,
    u16* __restrict__ Ch, u16* __restrict__ Cl)
{
    __shared__ __align__(16) u16 lds[2 * 2 * 1280];   // [buf][h/l][32*40]
    const int p = blockIdx.x & 1;
    const float* __restrict__ A = p ? A1 : A0;
    const u16* __restrict__ Bp = p ? B1 : B0;
    const float* __restrict__ bias = p ? bias1 : bias0;
    const int coff = p * 64;
    const int lane = threadIdx.x;
    const int wrow = (blockIdx.x >> 1) * 32;
    const int r15 = lane & 15, g = lane >> 4;

    size_t aoff[4];
#pragma unroll
    for (int i = 0; i < 4; i++) {
        int row = wrow + (lane >> 3) + 8 * i;
        row = row < NN ? row : NN - 1;
        aoff[i] = (size_t)row * 768 + (lane & 7) * 4;
    }
    // fragment-major B: element (t, ni, lane, j) at ((t*4+ni)*64 + lane)*8 + j
    size_t boff[4];
#pragma unroll
    for (int ni = 0; ni < 4; ni++)
        boff[ni] = (size_t)(ni * 64 + lane) * 8;

    f32x4 acc[2][4];
#pragma unroll
    for (int mi = 0; mi < 2; mi++)
#pragma unroll
        for (int ni = 0; ni < 4; ni++) acc[mi][ni] = (f32x4){0.f, 0.f, 0.f, 0.f};

    float4 Ar0[4], Ar1[4];
    uint4 Bs0[4], Bs1[4];

    auto loadA = [&](int t, float4 (&d)[4]) {
#pragma unroll
        for (int i = 0; i < 4; i++) d[i] = *(const float4*)&A[aoff[i] + t * 32];
    };
    auto loadB = [&](int t, uint4 (&d)[4]) {
#pragma unroll
        for (int ni = 0; ni < 4; ni++) d[ni] = *(const uint4*)&Bp[boff[ni] + (size_t)t * 2048];
    };
    auto writeA = [&](const float4 (&s)[4], int buf) {
#pragma unroll
        for (int i = 0; i < 4; i++) {
            int row2 = (lane >> 3) + 8 * i;
            unsigned e0 = __float_as_uint(s[i].x), e1 = __float_as_uint(s[i].y),
                     e2 = __float_as_uint(s[i].z), e3 = __float_as_uint(s[i].w);
            unsigned h0 = __builtin_amdgcn_perm(e1, e0, 0x07060302u);
            unsigned h1 = __builtin_amdgcn_perm(e3, e2, 0x07060302u);
            unsigned q0 = __float_as_uint(s[i].x - __uint_as_float(e0 & 0xFFFF0000u));
            unsigned q1 = __float_as_uint(s[i].y - __uint_as_float(e1 & 0xFFFF0000u));
            unsigned q2 = __float_as_uint(s[i].z - __uint_as_float(e2 & 0xFFFF0000u));
            unsigned q3 = __float_as_uint(s[i].w - __uint_as_float(e3 & 0xFFFF0000u));
            unsigned l0 = __builtin_amdgcn_perm(q1, q0, 0x07060302u);
            unsigned l1 = __builtin_amdgcn_perm(q3, q2, 0x07060302u);
            int idx = buf * 2 * 1280 + row2 * 40 + (lane & 7) * 4;
            *(u64*)&lds[idx] = (u64)h0 | ((u64)h1 << 32);
            *(u64*)&lds[idx + 1280] = (u64)l0 | ((u64)l1 << 32);
        }
    };
    auto compute = [&](int buf, const uint4 (&Bv)[4]) {
        bf16x8 afh[2], afl[2];
#pragma unroll
        for (int mi = 0; mi < 2; mi++) {
            int row = mi * 16 + r15;
            int idx = buf * 2 * 1280 + row * 40 + g * 8;
            afh[mi] = *(const bf16x8*)&lds[idx];
            afl[mi] = *(const bf16x8*)&lds[idx + 1280];
        }
#pragma unroll
        for (int mi = 0; mi < 2; mi++)
#pragma unroll
            for (int ni = 0; ni < 4; ni++) {
                bf16x8 bb = __builtin_bit_cast(bf16x8, Bv[ni]);
                acc[mi][ni] = __builtin_amdgcn_mfma_f32_16x16x32_bf16(afh[mi], bb, acc[mi][ni], 0, 0, 0);
                acc[mi][ni] = __builtin_amdgcn_mfma_f32_16x16x32_bf16(afl[mi], bb, acc[mi][ni], 0, 0, 0);
            }
    };

    // prologue
    loadA(0, Ar0); loadB(0, Bs0);
    writeA(Ar0, 0);
    loadA(1, Ar1); loadB(1, Bs1);
    // steady: t = 0..21 (NT=24)
    for (int tt = 0; tt < 11; ++tt) {
        int t0 = 2 * tt;
        loadA(t0 + 2, Ar0);
        compute(0, Bs0);
        loadB(t0 + 2, Bs0);
        writeA(Ar1, 1);
        loadA(t0 + 3, Ar1);
        compute(1, Bs1);
        loadB(t0 + 3, Bs1);
        writeA(Ar0, 0);
    }
    compute(0, Bs0);     // t=22
    writeA(Ar1, 1);      // tile 23 -> buf1
    compute(1, Bs1);     // t=23

    // ---- coalesced epilogue: acc -> LDS (h & l planes) -> 16B stores ----
    u16* tlh = &lds[0];             // 32 x 72 u16 (pad 8) per plane
    u16* tll = tlh + 2304;
#pragma unroll
    for (int mi = 0; mi < 2; mi++) {
#pragma unroll
        for (int ni = 0; ni < 4; ni++) {
            int col = ni * 16 + r15;
            float bsv = bias[col];
#pragma unroll
            for (int r = 0; r < 4; r++) {
                int row = mi * 16 + g * 4 + r;
                float v = acc[mi][ni][r] + bsv;
                v = v > 0.f ? v : 0.01f * v;   // lrelu
                u16 h, l; split_tr(v, h, l);
                tlh[row * 72 + col] = h;
                tll[row * 72 + col] = l;
            }
        }
    }
    asm volatile("s_waitcnt lgkmcnt(0)" ::: "memory");
    __builtin_amdgcn_sched_barrier(0);
    {
        int row = lane >> 1, cb = (lane & 1) * 32;
        int grow = wrow + row;
        if (grow < NN) {
#pragma unroll
            for (int j = 0; j < 4; j++) {
                uint4 hv = *(const uint4*)&tlh[row * 72 + cb + j * 8];
                uint4 lv = *(const uint4*)&tll[row * 72 + cb + j * 8];
                *(uint4*)&Ch[(size_t)grow * HD + coff + cb + j * 8] = hv;
                *(uint4*)&Cl[(size_t)grow * HD + coff + cb + j * 8] = lv;
            }
        }
    }
}

// ---- weight RNE-round+transpose: W f32 [K][Ncol] -> T bf16 [colOff+n][K] ----
__global__ void conv_w(const float* __restrict__ W, int K, int Ncol,
                       u16* __restrict__ Th, int colOff)
{
    int i = blockIdx.x * 256 + threadIdx.x;
    if (i >= K * Ncol) return;
    int k = i / Ncol, n = i % Ncol;
    Th[(size_t)(colOff + n) * K + k] = f2bf_rne(W[i]);
}

// ---- projection weights -> fragment-major: Bf[((t*4+ni)*64+lane)*8+j], K=768, Ncol=64 ----
__global__ void conv_wf(const float* __restrict__ W, u16* __restrict__ Bf)
{
    int i = blockIdx.x * 256 + threadIdx.x;
    if (i >= 768 * 64) return;
    int k = i >> 6, n = i & 63;
    int t = k >> 5, kk = k & 31, g = kk >> 3, j = kk & 7;
    int lane = g * 16 + (n & 15), ni = n >> 4;
    Bf[(size_t)((t * 4 + ni) * 64 + lane) * 8 + j] = f2bf_rne(W[i]);
}

// ---------------- small f32 GEMM (K=5/3), bf16-pair out ----------------
template<int BM, int BN, int BK, int TM, int TN>
__global__ __launch_bounds__(256) void gemm_f32s(
    const float* __restrict__ A, int lda,
    const float* __restrict__ B, int ldb,
    const float* __restrict__ bias,
    u16* __restrict__ Ch, u16* __restrict__ Cl, int coff,
    int M, int Ncol, int K)
{
    constexpr int TX = BN / TN;
    __shared__ float As[BK][BM + 4];
    __shared__ float Bs[BK][BN + 4];
    const int tid = threadIdx.x;
    const int tx = tid % TX, ty = tid / TX;
    const int brow = blockIdx.y * BM;
    const int bcol = blockIdx.x * BN;
    float acc[TM][TN];
#pragma unroll
    for (int i = 0; i < TM; i++)
#pragma unroll
        for (int j = 0; j < TN; j++) acc[i][j] = 0.f;
    for (int k0 = 0; k0 < K; k0 += BK) {
#pragma unroll
        for (int idx = tid; idx < BM * BK; idx += 256) {
            int m = idx / BK, k = idx % BK;
            int gr = brow + m, gk = k0 + k;
            As[k][m] = (gr < M && gk < K) ? A[(size_t)gr * lda + gk] : 0.f;
        }
#pragma unroll
        for (int idx = tid; idx < BK * BN; idx += 256) {
            int k = idx / BN, n = idx % BN;
            int gk = k0 + k, gc = bcol + n;
            Bs[k][n] = (gk < K && gc < Ncol) ? B[(size_t)gk * ldb + gc] : 0.f;
        }
        __syncthreads();
#pragma unroll
        for (int k = 0; k < BK; k++) {
            float a[TM], b[TN];
#pragma unroll
            for (int i = 0; i < TM; i++) a[i] = As[k][ty * TM + i];
#pragma unroll
            for (int j = 0; j < TN; j++) b[j] = Bs[k][tx * TN + j];
#pragma unroll
            for (int i = 0; i < TM; i++)
#pragma unroll
                for (int j = 0; j < TN; j++) acc[i][j] = fmaf(a[i], b[j], acc[i][j]);
        }
        __syncthreads();
    }
#pragma unroll
    for (int i = 0; i < TM; i++) {
        int gr = brow + ty * TM + i;
        if (gr >= M) continue;
#pragma unroll
        for (int j = 0; j < TN; j++) {
            int gc = bcol + tx * TN + j;
            if (gc >= Ncol) continue;
            float v = acc[i][j] + bias[gc];
            v = v > 0.f ? v : 0.01f * v;
            u16 h, l; split_tr(v, h, l);
            Ch[(size_t)gr * HD + coff + gc] = h;
            Cl[(size_t)gr * HD + coff + gc] = l;
        }
    }
}

// ---------------- CSR build ----------------
__global__ void count_seg(const int* __restrict__ ei, const int* __restrict__ et,
                          int* __restrict__ segc)
{
    int e = blockIdx.x * blockDim.x + threadIdx.x;
    if (e < EE) {
        int dst = ei[EE + e];
        int r = et[e];
        atomicAdd(&segc[r * NN + dst], 1);
    }
}

__global__ __launch_bounds__(256) void scan_local(const int* __restrict__ segc,
                                                  int* __restrict__ offs,
                                                  int* __restrict__ bsum)
{
    int b = blockIdx.x;
    int base = b * CHUNK;
    int tid = threadIdx.x;
    int lane = tid & 63, wave = tid >> 6;
    __shared__ int wsum[4];
    int vals[8];
    int i0 = base + tid * 8;
    int s = 0;
    if (i0 + 7 < NSEG) {
        int4 v0 = *(const int4*)&segc[i0];
        int4 v1 = *(const int4*)&segc[i0 + 4];
        vals[0] = v0.x; vals[1] = v0.y; vals[2] = v0.z; vals[3] = v0.w;
        vals[4] = v1.x; vals[5] = v1.y; vals[6] = v1.z; vals[7] = v1.w;
    } else {
#pragma unroll
        for (int j = 0; j < 8; j++) vals[j] = (i0 + j < NSEG) ? segc[i0 + j] : 0;
    }
#pragma unroll
    for (int j = 0; j < 8; j++) s += vals[j];
    int v = s;
#pragma unroll
    for (int off = 1; off < 64; off <<= 1) {
        int u = __shfl_up(v, off);
        if (lane >= off) v += u;
    }
    if (lane == 63) wsum[wave] = v;
    __syncthreads();
    int wbase = 0;
#pragma unroll
    for (int ww = 0; ww < 4; ww++) if (ww < wave) wbase += wsum[ww];
    int run = wbase + v - s;
#pragma unroll
    for (int j = 0; j < 8; j++) {
        run += vals[j];
        int i = i0 + j;
        if (i < NSEG) offs[i + 1] = run;
    }
    if (tid == 0) {
        int t = 0;
#pragma unroll
        for (int ww = 0; ww < 4; ww++) t += wsum[ww];
        bsum[b] = t;
    }
}

__global__ void scan_bsum(const int* __restrict__ bsum, int* __restrict__ bbase)
{
    int lane = threadIdx.x;
    int c = (lane < NB) ? bsum[lane] : 0;
    int v = c;
#pragma unroll
    for (int off = 1; off < 64; off <<= 1) {
        int u = __shfl_up(v, off);
        if (lane >= off) v += u;
    }
    if (lane < NB) bbase[lane] = v - c;
}

__global__ void add_base(int* __restrict__ offs, const int* __restrict__ bbase)
{
    int i = blockIdx.x * blockDim.x + threadIdx.x;
    if (i < NSEG) offs[i + 1] += bbase[i / CHUNK];
    if (i == 0) offs[0] = 0;
}

__global__ void fill_src(const int* __restrict__ ei, const int* __restrict__ et,
                         const int* __restrict__ offs, int* __restrict__ cursor,
                         int* __restrict__ src_list)
{
    int e = blockIdx.x * blockDim.x + threadIdx.x;
    if (e < EE) {
        int src = ei[e];
        int dst = ei[EE + e];
        int s = et[e] * NN + dst;
        int pos = offs[s] + atomicAdd(&cursor[s], 1);
        src_list[pos] = src;
    }
}

// ---------------- gather: v = base + sum_r mean(hrel_bf16) ----------------
// OUTM 0: write bf16 hi/lo pair (next layer input).
// OUTM 1: fused head: logits[d,c] = v . w_out[:,c] + b_out[c]
template<int OUTM>
__global__ __launch_bounds__(256) void gather_mean_b(
    const u16* __restrict__ hrelb,
    const int* __restrict__ offs,
    const int* __restrict__ src_list,
    const float* __restrict__ basein,
    u16* __restrict__ Oh, u16* __restrict__ Ol,
    const float* __restrict__ wout, const float* __restrict__ bout,
    float* __restrict__ logits)
{
    int d = blockIdx.x * 4 + (threadIdx.x >> 6);
    if (d >= NN) return;
    int lane = threadIdx.x & 63;
    f32x4 acc = {0.f, 0.f, 0.f, 0.f};
#pragma unroll
    for (int r = 0; r < 2; r++) {
        int s = r * NN + d;
        int start = offs[s], end = offs[s + 1];
        if (start == end) continue;
        f32x4 a = {0.f, 0.f, 0.f, 0.f};
        const u16* hb = hrelb + (size_t)r * NN * HD;
        for (int i = start; i < end; i++) {
            int src = src_list[i];
            uint2 wv = *(const uint2*)(hb + (size_t)src * HD + lane * 4);
            a.x += __uint_as_float(wv.x << 16);
            a.y += __uint_as_float(wv.x & 0xFFFF0000u);
            a.z += __uint_as_float(wv.y << 16);
            a.w += __uint_as_float(wv.y & 0xFFFF0000u);
        }
        float inv = 1.0f / (float)(end - start);
        acc.x += a.x * inv; acc.y += a.y * inv;
        acc.z += a.z * inv; acc.w += a.w * inv;
    }
    float4 b = ((const float4*)(basein + (size_t)d * HD))[lane];
    float v0 = b.x + acc.x, v1 = b.y + acc.y, v2 = b.z + acc.z, v3 = b.w + acc.w;
    if (OUTM == 0) {
        u16 h0, l0, h1, l1, h2, l2, h3, l3;
        split_tr(v0, h0, l0); split_tr(v1, h1, l1);
        split_tr(v2, h2, l2); split_tr(v3, h3, l3);
        uint2 uh, ul;
        uh.x = (unsigned)h0 | ((unsigned)h1 << 16);
        uh.y = (unsigned)h2 | ((unsigned)h3 << 16);
        ul.x = (unsigned)l0 | ((unsigned)l1 << 16);
        ul.y = (unsigned)l2 | ((unsigned)l3 << 16);
        *(uint2*)(Oh + (size_t)d * HD + lane * 4) = uh;
        *(uint2*)(Ol + (size_t)d * HD + lane * 4) = ul;
    } else {
        int k = lane * 4;
        float a0 = v0 * wout[(k + 0) * 2 + 0] + v1 * wout[(k + 1) * 2 + 0]
                 + v2 * wout[(k + 2) * 2 + 0] + v3 * wout[(k + 3) * 2 + 0];
        float a1 = v0 * wout[(k + 0) * 2 + 1] + v1 * wout[(k + 1) * 2 + 1]
                 + v2 * wout[(k + 2) * 2 + 1] + v3 * wout[(k + 3) * 2 + 1];
#pragma unroll
        for (int off = 32; off > 0; off >>= 1) {
            a0 += __shfl_down(a0, off);
            a1 += __shfl_down(a1, off);
        }
        if (lane == 0) {
            logits[(size_t)d * 2 + 0] = a0 + bout[0];
            logits[(size_t)d * 2 + 1] = a1 + bout[1];
        }
    }
}

extern "C" void kernel_launch(void* const* d_in, const int* in_sizes, int n_in,
                              void* d_out, int out_size, void* d_ws, size_t ws_size,
                              hipStream_t stream)
{
    const float* des   = (const float*)d_in[0];
    const float* tweet = (const float*)d_in[1];
    const float* nump  = (const float*)d_in[2];
    const float* catp  = (const float*)d_in[3];
    const int*   ei    = (const int*)d_in[4];
    const int*   et    = (const int*)d_in[5];
    const float* w_des = (const float*)d_in[6],  *b_des = (const float*)d_in[7];
    const float* w_tw  = (const float*)d_in[8],  *b_tw  = (const float*)d_in[9];
    const float* w_num = (const float*)d_in[10], *b_num = (const float*)d_in[11];
    const float* w_cat = (const float*)d_in[12], *b_cat = (const float*)d_in[13];
    const float* w_in  = (const float*)d_in[14], *b_in  = (const float*)d_in[15];
    const float* weight1 = (const float*)d_in[16], *root1 = (const float*)d_in[17], *bias1 = (const float*)d_in[18];
    const float* weight2 = (const float*)d_in[19], *root2 = (const float*)d_in[20], *bias2 = (const float*)d_in[21];
    const float* w_out = (const float*)d_in[22], *b_out = (const float*)d_in[23];
    float* outp = (float*)d_out;

    const int HSZ = HD * HD, PSZ = 768 * 64;

    // ---- workspace carve-up ----
    float* base  = (float*)d_ws;                       // [N,HD] f32
    u16*   hrelb = (u16*)(base + (size_t)NN * HD);     // [2,N,HD] bf16
    u16*   xh    = hrelb + (size_t)2 * NN * HD;
    u16*   xl    = xh + (size_t)NN * HD;
    u16*   yh    = xl + (size_t)NN * HD;
    u16*   yl    = yh + (size_t)NN * HD;
    int*   offs  = (int*)(yl + (size_t)NN * HD);
    int*   segc  = offs + (NSEG + 1);
    int*   srcl  = segc + NSEG;
    int*   bsum  = srcl + EE;
    int*   bbase = bsum + NB;
    uintptr_t wp = ((uintptr_t)(bbase + NB) + 15) & ~(uintptr_t)15;
    u16* desB = (u16*)wp;
    u16* twB  = desB + PSZ;
    u16* winB = twB + PSZ;
    u16* cat1 = winB + HSZ;
    u16* cat2 = cat1 + 3 * HSZ;

    // ---- CSR build ----
    hipMemsetAsync(segc, 0, NSEG * sizeof(int), stream);
    count_seg<<<(EE + 255) / 256, 256, 0, stream>>>(ei, et, segc);
    scan_local<<<NB, 256, 0, stream>>>(segc, offs, bsum);
    scan_bsum<<<1, 64, 0, stream>>>(bsum, bbase);
    add_base<<<(NSEG + 255) / 256, 256, 0, stream>>>(offs, bbase);
    hipMemsetAsync(segc, 0, NSEG * sizeof(int), stream);
    fill_src<<<(EE + 255) / 256, 256, 0, stream>>>(ei, et, offs, segc, srcl);

    // ---- weight conversion ----
    conv_wf<<<(PSZ + 255) / 256, 256, 0, stream>>>(w_des, desB);   // fragment-major
    conv_wf<<<(PSZ + 255) / 256, 256, 0, stream>>>(w_tw,  twB);    // fragment-major
    conv_w<<<(HSZ + 255) / 256, 256, 0, stream>>>(w_in, HD, HD, winB, 0);
    conv_w<<<(HSZ + 255) / 256, 256, 0, stream>>>(weight1,       HD, HD, cat1, 0);
    conv_w<<<(HSZ + 255) / 256, 256, 0, stream>>>(weight1 + HSZ, HD, HD, cat1, 256);
    conv_w<<<(HSZ + 255) / 256, 256, 0, stream>>>(root1,         HD, HD, cat1, 512);
    conv_w<<<(HSZ + 255) / 256, 256, 0, stream>>>(weight2,       HD, HD, cat2, 0);
    conv_w<<<(HSZ + 255) / 256, 256, 0, stream>>>(weight2 + HSZ, HD, HD, cat2, 256);
    conv_w<<<(HSZ + 255) / 256, 256, 0, stream>>>(root2,         HD, HD, cat2, 512);

    const int NYB = (NN + 127) / 128;    // 391 (128-row blocks)
    const int NWB = (NN + 31) / 32;      // 1563 (32-row wave blocks)

    // ---- fused feature projections (des+tweet) -> xh/xl (wave-autonomous, 64-thr) ----
    gemm_projW<<<2 * NWB, 64, 0, stream>>>(des, tweet, desB, twB, b_des, b_tw, xh, xl);
    dim3 gsmall(1, (NN + 63) / 64);
    gemm_f32s<64, 64, 8, 4, 4><<<gsmall, 256, 0, stream>>>(nump, 5, w_num, 64, b_num, xh, xl, 128, NN, 64, 5);
    gemm_f32s<64, 64, 8, 4, 4><<<gsmall, 256, 0, stream>>>(catp, 3, w_cat, 64, b_cat, xh, xl, 192, NN, 64, 3);

    // ---- y = lrelu(x @ w_in + b_in) -> yh/yl ----
    gemm_bf16L<1><<<2 * NYB, 256, 0, stream>>>(xh, xl, winB, b_in, yh, yl, nullptr, NN, 2);

    // ---- layer 1: fused [W_r0|W_r1|root1] -> hrelb (bf16) + base (f32) ----
    gemm_bf16L<2><<<6 * NYB, 256, 0, stream>>>(yh, yl, cat1, bias1, hrelb, nullptr, base, NN, 6);
    gather_mean_b<0><<<(NN + 3) / 4, 256, 0, stream>>>(hrelb, offs, srcl, base, xh, xl, nullptr, nullptr, nullptr);

    // ---- layer 2 + fused output head ----
    gemm_bf16L<2><<<6 * NYB, 256, 0, stream>>>(xh, xl, cat2, bias2, hrelb, nullptr, base, NN, 6);
    gather_mean_b<1><<<(NN + 3) / 4, 256, 0, stream>>>(hrelb, offs, srcl, base, nullptr, nullptr, w_out, b_out, outp);
}

// Round 15
// 592.541 us; speedup vs baseline: 1.7140x; 1.0053x over previous
//
#include <hip/hip_runtime.h>

#define NN 50000
#define EE 800000
#define HD 256
#define NSEG (2 * NN)
#define CHUNK 2048
#define NB ((NSEG + CHUNK - 1) / CHUNK)

typedef unsigned short u16;
typedef unsigned long long u64;
typedef short bf16x8 __attribute__((ext_vector_type(8)));
typedef float f32x4 __attribute__((ext_vector_type(4)));

__device__ __forceinline__ u16 f2bf_rne(float f) {
    unsigned u = __float_as_uint(f);
    return (u16)((u + 0x7FFF + ((u >> 16) & 1)) >> 16);
}
// trunc hi + RNE residual: (h,l) represents v to ~2^-17 relative
__device__ __forceinline__ void split_tr(float v, u16& h, u16& l) {
    unsigned u = __float_as_uint(v);
    h = (u16)(u >> 16);
    l = f2bf_rne(v - __uint_as_float(u & 0xFFFF0000u));
}

// bijective XCD-chunked swizzle (m204)
__device__ __forceinline__ int xcd_swizzle(int orig, int nwg) {
    int q = nwg >> 3, r = nwg & 7;
    int xcd = orig & 7, idx = orig >> 3;
    return (xcd < r ? xcd * (q + 1) : r * (q + 1) + (xcd - r) * q) + idx;
}

// async global->LDS, 16B per lane; LDS dest = wave-uniform base + lane*16
__device__ __forceinline__ void g2l16(const void* g, void* l) {
    __builtin_amdgcn_global_load_lds(
        (const __attribute__((address_space(1))) void*)g,
        (__attribute__((address_space(3))) void*)l, 16, 0, 0);
}

// bank swizzle for 64B-row bf16 tiles
__device__ __forceinline__ int swz2(int row) { return (row & 2) | ((row >> 2) & 1); }

// stage one 128x32 bf16 tile from G[rc][K] (k-contiguous), source-swizzled
__device__ __forceinline__ void stage_bf16(const u16* __restrict__ G, u16* S,
                                           int base_rc, int maxrc, int K, int k0, int tid) {
#pragma unroll
    for (int s = 0; s < 2; s++) {
        int slot = tid + s * 256;
        int row = slot >> 2, gg = slot & 3;
        int gsrc = gg ^ swz2(row);
        int arow = base_rc + row; arow = arow < maxrc ? arow : maxrc - 1;
        g2l16(G + (size_t)arow * K + k0 + gsrc * 8, S + ((tid & ~63) + s * 256) * 8);
    }
}

// ============ counted-vmcnt dbuf bf16 GEMM (round-10 proven): A hi/lo pair, B bf16 ====
// acc = Ah*Bh + Al*Bh. BM=BN=128, 4 waves 2x2, MFMA 16x16x32, k-map k=k0+g*8+j.
// MODE 1: lrelu -> bf16 pair out (w_in). MODE 2: relu; col<512 -> bf16 hrel; else f32 O2.
template<int MODE>
__global__ __launch_bounds__(256) void gemm_bf16L(
    const u16* __restrict__ Ahg, const u16* __restrict__ Alg,
    const u16* __restrict__ Bhg,
    const float* __restrict__ bias,
    u16* __restrict__ O1h, u16* __restrict__ O1l, float* __restrict__ O2,
    int M, int nxb)
{
    __shared__ __align__(16) u16 sAh[2][128 * 32];
    __shared__ __align__(16) u16 sAl[2][128 * 32];
    __shared__ __align__(16) u16 sBh[2][128 * 32];
    const int wgid = xcd_swizzle(blockIdx.x, gridDim.x);
    const int brow = (wgid / nxb) * 128, bcol = (wgid % nxb) * 128;
    const int tid = threadIdx.x, lane = tid & 63, w = tid >> 6;
    const int wr = w >> 1, wc = w & 1;
    const int r15 = lane & 15, g = lane >> 4;
    const int fsw = (g ^ swz2(r15)) * 8;

    f32x4 acc[4][4];
#pragma unroll
    for (int mi = 0; mi < 4; mi++)
#pragma unroll
        for (int ni = 0; ni < 4; ni++) acc[mi][ni] = (f32x4){0.f, 0.f, 0.f, 0.f};

    auto stage_step = [&](int k0, int b) {       // 6 VMEM instr per thread
        stage_bf16(Ahg, sAh[b], brow, M, 256, k0, tid);
        stage_bf16(Alg, sAl[b], brow, M, 256, k0, tid);
        stage_bf16(Bhg, sBh[b], bcol, 1 << 30, 256, k0, tid);
    };
    auto compute_step = [&](int b) {
        bf16x8 afh[4], afl[4], bfh[4];
#pragma unroll
        for (int mi = 0; mi < 4; mi++) {
            int idx = (wr * 64 + mi * 16 + r15) * 32 + fsw;
            afh[mi] = *(const bf16x8*)&sAh[b][idx];
            afl[mi] = *(const bf16x8*)&sAl[b][idx];
        }
#pragma unroll
        for (int ni = 0; ni < 4; ni++) {
            int idx = (wc * 64 + ni * 16 + r15) * 32 + fsw;
            bfh[ni] = *(const bf16x8*)&sBh[b][idx];
        }
#pragma unroll
        for (int mi = 0; mi < 4; mi++)
#pragma unroll
            for (int ni = 0; ni < 4; ni++)
                acc[mi][ni] = __builtin_amdgcn_mfma_f32_16x16x32_bf16(afh[mi], bfh[ni], acc[mi][ni], 0, 0, 0);
#pragma unroll
        for (int mi = 0; mi < 4; mi++)
#pragma unroll
            for (int ni = 0; ni < 4; ni++)
                acc[mi][ni] = __builtin_amdgcn_mfma_f32_16x16x32_bf16(afl[mi], bfh[ni], acc[mi][ni], 0, 0, 0);
    };

    stage_step(0, 0);
    stage_step(32, 1);
#pragma unroll
    for (int t = 0; t < 7; t++) {
        asm volatile("s_waitcnt vmcnt(6)" ::: "memory");   // drain buf[t&1] only
        __builtin_amdgcn_s_barrier();
        compute_step(t & 1);
        __builtin_amdgcn_s_barrier();
        if (t + 2 < 8) stage_step((t + 2) * 32, t & 1);
    }
    asm volatile("s_waitcnt vmcnt(0)" ::: "memory");
    __builtin_amdgcn_s_barrier();
    compute_step(1);

#pragma unroll
    for (int mi = 0; mi < 4; mi++) {
#pragma unroll
        for (int ni = 0; ni < 4; ni++) {
            int col = bcol + wc * 64 + ni * 16 + r15;
            float bsv = bias[col & (HD - 1)];
            int rbase = brow + wr * 64 + mi * 16 + g * 4;
#pragma unroll
            for (int r = 0; r < 4; r++) {
                int grow = rbase + r;
                if (grow >= M) continue;
                float v = acc[mi][ni][r] + bsv;
                if (MODE == 1) {
                    v = v > 0.f ? v : 0.01f * v;   // lrelu
                    u16 h, l; split_tr(v, h, l);
                    O1h[(size_t)grow * HD + col] = h;
                    O1l[(size_t)grow * HD + col] = l;
                } else {
                    v = fmaxf(v, 0.f);             // relu
                    if (col < 2 * HD) {
                        O1h[((size_t)(col >> 8) * NN + grow) * HD + (col & (HD - 1))] = f2bf_rne(v);
                    } else {
                        O2[(size_t)grow * HD + (col & (HD - 1))] = v;
                    }
                }
            }
        }
    }
}

// ===================== wave-autonomous dual-projection GEMM (K=768) =====================
// 128-thread blocks = 2 INDEPENDENT waves (no barriers). Each wave: 16 rows x 64 cols.
// A f32 coalesced->regs->perm-convert->private LDS (dbuf, pad 40). B fragment-major:
// one coalesced 1KB wave load per (t,ni). Coalesced LDS-transpose epilogue. lrelu out.
__global__ __launch_bounds__(128) void gemm_projW(
    const float* __restrict__ A0, const float* __restrict__ A1,
    const u16* __restrict__ B0, const u16* __restrict__ B1,
    const float* __restrict__ bias0, const float* __restrict__ bias1,
    u16* __restrict__ Ch, u16* __restrict__ Cl)
{
    __shared__ __align__(16) u16 lds[2 * 2 * 2 * 640];   // [wave][buf][h/l][16*40]
    const int p = blockIdx.x & 1;
    const float* __restrict__ A = p ? A1 : A0;
    const u16* __restrict__ Bp = p ? B1 : B0;
    const float* __restrict__ bias = p ? bias1 : bias0;
    const int coff = p * 64;
    const int lane = threadIdx.x & 63, w = threadIdx.x >> 6;
    const int wrow = (blockIdx.x >> 1) * 32 + w * 16;
    const int r15 = lane & 15, g = lane >> 4;
    const int lbase = w * 2560;      // u16 units

    size_t aoff[2];
#pragma unroll
    for (int i = 0; i < 2; i++) {
        int row = wrow + (lane >> 3) + 8 * i;
        row = row < NN ? row : NN - 1;
        aoff[i] = (size_t)row * 768 + (lane & 7) * 4;
    }
    // fragment-major B: element (t, ni, lane, j) at ((t*4+ni)*64 + lane)*8 + j
    size_t boff[4];
#pragma unroll
    for (int ni = 0; ni < 4; ni++)
        boff[ni] = (size_t)(ni * 64 + lane) * 8;

    f32x4 acc[4];
#pragma unroll
    for (int ni = 0; ni < 4; ni++) acc[ni] = (f32x4){0.f, 0.f, 0.f, 0.f};

    float4 Ar0[2], Ar1[2];
    uint4 Bs0[4], Bs1[4];

    auto loadA = [&](int t, float4 (&d)[2]) {
#pragma unroll
        for (int i = 0; i < 2; i++) d[i] = *(const float4*)&A[aoff[i] + t * 32];
    };
    auto loadB = [&](int t, uint4 (&d)[4]) {
#pragma unroll
        for (int ni = 0; ni < 4; ni++) d[ni] = *(const uint4*)&Bp[boff[ni] + (size_t)t * 2048];
    };
    auto writeA = [&](const float4 (&s)[2], int buf) {
#pragma unroll
        for (int i = 0; i < 2; i++) {
            int row2 = (lane >> 3) + 8 * i;
            unsigned e0 = __float_as_uint(s[i].x), e1 = __float_as_uint(s[i].y),
                     e2 = __float_as_uint(s[i].z), e3 = __float_as_uint(s[i].w);
            unsigned h0 = __builtin_amdgcn_perm(e1, e0, 0x07060302u);
            unsigned h1 = __builtin_amdgcn_perm(e3, e2, 0x07060302u);
            unsigned q0 = __float_as_uint(s[i].x - __uint_as_float(e0 & 0xFFFF0000u));
            unsigned q1 = __float_as_uint(s[i].y - __uint_as_float(e1 & 0xFFFF0000u));
            unsigned q2 = __float_as_uint(s[i].z - __uint_as_float(e2 & 0xFFFF0000u));
            unsigned q3 = __float_as_uint(s[i].w - __uint_as_float(e3 & 0xFFFF0000u));
            unsigned l0 = __builtin_amdgcn_perm(q1, q0, 0x07060302u);
            unsigned l1 = __builtin_amdgcn_perm(q3, q2, 0x07060302u);
            int idx = lbase + buf * 1280 + row2 * 40 + (lane & 7) * 4;
            *(u64*)&lds[idx] = (u64)h0 | ((u64)h1 << 32);
            *(u64*)&lds[idx + 640] = (u64)l0 | ((u64)l1 << 32);
        }
    };
    auto compute = [&](int buf, const uint4 (&Bv)[4]) {
        bf16x8 afh, afl;
        {
            int idx = lbase + buf * 1280 + r15 * 40 + g * 8;
            afh = *(const bf16x8*)&lds[idx];
            afl = *(const bf16x8*)&lds[idx + 640];
        }
#pragma unroll
        for (int ni = 0; ni < 4; ni++) {
            bf16x8 bb = __builtin_bit_cast(bf16x8, Bv[ni]);
            acc[ni] = __builtin_amdgcn_mfma_f32_16x16x32_bf16(afh, bb, acc[ni], 0, 0, 0);
            acc[ni] = __builtin_amdgcn_mfma_f32_16x16x32_bf16(afl, bb, acc[ni], 0, 0, 0);
        }
    };

    // prologue (NT = 24)
    loadA(0, Ar0); loadB(0, Bs0);
    writeA(Ar0, 0);
    loadA(1, Ar1); loadB(1, Bs1);
    // steady: t = 0..21
    for (int tt = 0; tt < 11; ++tt) {
        int t0 = 2 * tt;
        loadA(t0 + 2, Ar0);
        compute(0, Bs0);
        loadB(t0 + 2, Bs0);
        writeA(Ar1, 1);
        loadA(t0 + 3, Ar1);
        compute(1, Bs1);
        loadB(t0 + 3, Bs1);
        writeA(Ar0, 0);
    }
    compute(0, Bs0);     // t=22
    writeA(Ar1, 1);      // tile 23 -> buf1
    compute(1, Bs1);     // t=23

    // ---- coalesced epilogue: acc -> wave-private LDS (h & l planes) -> 16B stores ----
    u16* tlh = &lds[lbase];          // 16 x 72 u16 (pad 8) per plane
    u16* tll = tlh + 1152;
#pragma unroll
    for (int ni = 0; ni < 4; ni++) {
        int col = ni * 16 + r15;
        float bsv = bias[col];
#pragma unroll
        for (int r = 0; r < 4; r++) {
            int row = g * 4 + r;
            float v = acc[ni][r] + bsv;
            v = v > 0.f ? v : 0.01f * v;   // lrelu
            u16 h, l; split_tr(v, h, l);
            tlh[row * 72 + col] = h;
            tll[row * 72 + col] = l;
        }
    }
    asm volatile("s_waitcnt lgkmcnt(0)" ::: "memory");
    __builtin_amdgcn_sched_barrier(0);
    {
        int row = lane >> 2, cb = (lane & 3) * 16;
        int grow = wrow + row;
        if (grow < NN) {
#pragma unroll
            for (int j = 0; j < 2; j++) {
                uint4 hv = *(const uint4*)&tlh[row * 72 + cb + j * 8];
                uint4 lv = *(const uint4*)&tll[row * 72 + cb + j * 8];
                *(uint4*)&Ch[(size_t)grow * HD + coff + cb + j * 8] = hv;
                *(uint4*)&Cl[(size_t)grow * HD + coff + cb + j * 8] = lv;
            }
        }
    }
}

// ---- weight RNE-round+transpose: W f32 [K][Ncol] -> T bf16 [colOff+n][K] ----
__global__ void conv_w(const float* __restrict__ W, int K, int Ncol,
                       u16* __restrict__ Th, int colOff)
{
    int i = blockIdx.x * 256 + threadIdx.x;
    if (i >= K * Ncol) return;
    int k = i / Ncol, n = i % Ncol;
    Th[(size_t)(colOff + n) * K + k] = f2bf_rne(W[i]);
}

// ---- projection weights -> fragment-major: Bf[((t*4+ni)*64+lane)*8+j], K=768, Ncol=64 ----
__global__ void conv_wf(const float* __restrict__ W, u16* __restrict__ Bf)
{
    int i = blockIdx.x * 256 + threadIdx.x;
    if (i >= 768 * 64) return;
    int k = i >> 6, n = i & 63;
    int t = k >> 5, kk = k & 31, g = kk >> 3, j = kk & 7;
    int lane = g * 16 + (n & 15), ni = n >> 4;
    Bf[(size_t)((t * 4 + ni) * 64 + lane) * 8 + j] = f2bf_rne(W[i]);
}

// ---------------- small f32 GEMM (K=5/3), bf16-pair out ----------------
template<int BM, int BN, int BK, int TM, int TN>
__global__ __launch_bounds__(256) void gemm_f32s(
    const float* __restrict__ A, int lda,
    const float* __restrict__ B, int ldb,
    const float* __restrict__ bias,
    u16* __restrict__ Ch, u16* __restrict__ Cl, int coff,
    int M, int Ncol, int K)
{
    constexpr int TX = BN / TN;
    __shared__ float As[BK][BM + 4];
    __shared__ float Bs[BK][BN + 4];
    const int tid = threadIdx.x;
    const int tx = tid % TX, ty = tid / TX;
    const int brow = blockIdx.y * BM;
    const int bcol = blockIdx.x * BN;
    float acc[TM][TN];
#pragma unroll
    for (int i = 0; i < TM; i++)
#pragma unroll
        for (int j = 0; j < TN; j++) acc[i][j] = 0.f;
    for (int k0 = 0; k0 < K; k0 += BK) {
#pragma unroll
        for (int idx = tid; idx < BM * BK; idx += 256) {
            int m = idx / BK, k = idx % BK;
            int gr = brow + m, gk = k0 + k;
            As[k][m] = (gr < M && gk < K) ? A[(size_t)gr * lda + gk] : 0.f;
        }
#pragma unroll
        for (int idx = tid; idx < BK * BN; idx += 256) {
            int k = idx / BN, n = idx % BN;
            int gk = k0 + k, gc = bcol + n;
            Bs[k][n] = (gk < K && gc < Ncol) ? B[(size_t)gk * ldb + gc] : 0.f;
        }
        __syncthreads();
#pragma unroll
        for (int k = 0; k < BK; k++) {
            float a[TM], b[TN];
#pragma unroll
            for (int i = 0; i < TM; i++) a[i] = As[k][ty * TM + i];
#pragma unroll
            for (int j = 0; j < TN; j++) b[j] = Bs[k][tx * TN + j];
#pragma unroll
            for (int i = 0; i < TM; i++)
#pragma unroll
                for (int j = 0; j < TN; j++) acc[i][j] = fmaf(a[i], b[j], acc[i][j]);
        }
        __syncthreads();
    }
#pragma unroll
    for (int i = 0; i < TM; i++) {
        int gr = brow + ty * TM + i;
        if (gr >= M) continue;
#pragma unroll
        for (int j = 0; j < TN; j++) {
            int gc = bcol + tx * TN + j;
            if (gc >= Ncol) continue;
            float v = acc[i][j] + bias[gc];
            v = v > 0.f ? v : 0.01f * v;
            u16 h, l; split_tr(v, h, l);
            Ch[(size_t)gr * HD + coff + gc] = h;
            Cl[(size_t)gr * HD + coff + gc] = l;
        }
    }
}

// ---------------- CSR build ----------------
__global__ void count_seg(const int* __restrict__ ei, const int* __restrict__ et,
                          int* __restrict__ segc)
{
    int e = blockIdx.x * blockDim.x + threadIdx.x;
    if (e < EE) {
        int dst = ei[EE + e];
        int r = et[e];
        atomicAdd(&segc[r * NN + dst], 1);
    }
}

__global__ __launch_bounds__(256) void scan_local(const int* __restrict__ segc,
                                                  int* __restrict__ offs,
                                                  int* __restrict__ bsum)
{
    int b = blockIdx.x;
    int base = b * CHUNK;
    int tid = threadIdx.x;
    int lane = tid & 63, wave = tid >> 6;
    __shared__ int wsum[4];
    int vals[8];
    int i0 = base + tid * 8;
    int s = 0;
    if (i0 + 7 < NSEG) {
        int4 v0 = *(const int4*)&segc[i0];
        int4 v1 = *(const int4*)&segc[i0 + 4];
        vals[0] = v0.x; vals[1] = v0.y; vals[2] = v0.z; vals[3] = v0.w;
        vals[4] = v1.x; vals[5] = v1.y; vals[6] = v1.z; vals[7] = v1.w;
    } else {
#pragma unroll
        for (int j = 0; j < 8; j++) vals[j] = (i0 + j < NSEG) ? segc[i0 + j] : 0;
    }
#pragma unroll
    for (int j = 0; j < 8; j++) s += vals[j];
    int v = s;
#pragma unroll
    for (int off = 1; off < 64; off <<= 1) {
        int u = __shfl_up(v, off);
        if (lane >= off) v += u;
    }
    if (lane == 63) wsum[wave] = v;
    __syncthreads();
    int wbase = 0;
#pragma unroll
    for (int ww = 0; ww < 4; ww++) if (ww < wave) wbase += wsum[ww];
    int run = wbase + v - s;
#pragma unroll
    for (int j = 0; j < 8; j++) {
        run += vals[j];
        int i = i0 + j;
        if (i < NSEG) offs[i + 1] = run;
    }
    if (tid == 0) {
        int t = 0;
#pragma unroll
        for (int ww = 0; ww < 4; ww++) t += wsum[ww];
        bsum[b] = t;
    }
}

__global__ void scan_bsum(const int* __restrict__ bsum, int* __restrict__ bbase)
{
    int lane = threadIdx.x;
    int c = (lane < NB) ? bsum[lane] : 0;
    int v = c;
#pragma unroll
    for (int off = 1; off < 64; off <<= 1) {
        int u = __shfl_up(v, off);
        if (lane >= off) v += u;
    }
    if (lane < NB) bbase[lane] = v - c;
}

__global__ void add_base(int* __restrict__ offs, const int* __restrict__ bbase)
{
    int i = blockIdx.x * blockDim.x + threadIdx.x;
    if (i < NSEG) offs[i + 1] += bbase[i / CHUNK];
    if (i == 0) offs[0] = 0;
}

__global__ void fill_src(const int* __restrict__ ei, const int* __restrict__ et,
                         const int* __restrict__ offs, int* __restrict__ cursor,
                         int* __restrict__ src_list)
{
    int e = blockIdx.x * blockDim.x + threadIdx.x;
    if (e < EE) {
        int src = ei[e];
        int dst = ei[EE + e];
        int s = et[e] * NN + dst;
        int pos = offs[s] + atomicAdd(&cursor[s], 1);
        src_list[pos] = src;
    }
}

// ---------------- gather: v = base + sum_r mean(hrel_bf16) ----------------
// OUTM 0: write bf16 hi/lo pair (next layer input).
// OUTM 1: fused head: logits[d,c] = v . w_out[:,c] + b_out[c]
template<int OUTM>
__global__ __launch_bounds__(256) void gather_mean_b(
    const u16* __restrict__ hrelb,
    const int* __restrict__ offs,
    const int* __restrict__ src_list,
    const float* __restrict__ basein,
    u16* __restrict__ Oh, u16* __restrict__ Ol,
    const float* __restrict__ wout, const float* __restrict__ bout,
    float* __restrict__ logits)
{
    int d = blockIdx.x * 4 + (threadIdx.x >> 6);
    if (d >= NN) return;
    int lane = threadIdx.x & 63;
    f32x4 acc = {0.f, 0.f, 0.f, 0.f};
#pragma unroll
    for (int r = 0; r < 2; r++) {
        int s = r * NN + d;
        int start = offs[s], end = offs[s + 1];
        if (start == end) continue;
        f32x4 a = {0.f, 0.f, 0.f, 0.f};
        const u16* hb = hrelb + (size_t)r * NN * HD;
        for (int i = start; i < end; i++) {
            int src = src_list[i];
            uint2 wv = *(const uint2*)(hb + (size_t)src * HD + lane * 4);
            a.x += __uint_as_float(wv.x << 16);
            a.y += __uint_as_float(wv.x & 0xFFFF0000u);
            a.z += __uint_as_float(wv.y << 16);
            a.w += __uint_as_float(wv.y & 0xFFFF0000u);
        }
        float inv = 1.0f / (float)(end - start);
        acc.x += a.x * inv; acc.y += a.y * inv;
        acc.z += a.z * inv; acc.w += a.w * inv;
    }
    float4 b = ((const float4*)(basein + (size_t)d * HD))[lane];
    float v0 = b.x + acc.x, v1 = b.y + acc.y, v2 = b.z + acc.z, v3 = b.w + acc.w;
    if (OUTM == 0) {
        u16 h0, l0, h1, l1, h2, l2, h3, l3;
        split_tr(v0, h0, l0); split_tr(v1, h1, l1);
        split_tr(v2, h2, l2); split_tr(v3, h3, l3);
        uint2 uh, ul;
        uh.x = (unsigned)h0 | ((unsigned)h1 << 16);
        uh.y = (unsigned)h2 | ((unsigned)h3 << 16);
        ul.x = (unsigned)l0 | ((unsigned)l1 << 16);
        ul.y = (unsigned)l2 | ((unsigned)l3 << 16);
        *(uint2*)(Oh + (size_t)d * HD + lane * 4) = uh;
        *(uint2*)(Ol + (size_t)d * HD + lane * 4) = ul;
    } else {
        int k = lane * 4;
        float a0 = v0 * wout[(k + 0) * 2 + 0] + v1 * wout[(k + 1) * 2 + 0]
                 + v2 * wout[(k + 2) * 2 + 0] + v3 * wout[(k + 3) * 2 + 0];
        float a1 = v0 * wout[(k + 0) * 2 + 1] + v1 * wout[(k + 1) * 2 + 1]
                 + v2 * wout[(k + 2) * 2 + 1] + v3 * wout[(k + 3) * 2 + 1];
#pragma unroll
        for (int off = 32; off > 0; off >>= 1) {
            a0 += __shfl_down(a0, off);
            a1 += __shfl_down(a1, off);
        }
        if (lane == 0) {
            logits[(size_t)d * 2 + 0] = a0 + bout[0];
            logits[(size_t)d * 2 + 1] = a1 + bout[1];
        }
    }
}

extern "C" void kernel_launch(void* const* d_in, const int* in_sizes, int n_in,
                              void* d_out, int out_size, void* d_ws, size_t ws_size,
                              hipStream_t stream)
{
    const float* des   = (const float*)d_in[0];
    const float* tweet = (const float*)d_in[1];
    const float* nump  = (const float*)d_in[2];
    const float* catp  = (const float*)d_in[3];
    const int*   ei    = (const int*)d_in[4];
    const int*   et    = (const int*)d_in[5];
    const float* w_des = (const float*)d_in[6],  *b_des = (const float*)d_in[7];
    const float* w_tw  = (const float*)d_in[8],  *b_tw  = (const float*)d_in[9];
    const float* w_num = (const float*)d_in[10], *b_num = (const float*)d_in[11];
    const float* w_cat = (const float*)d_in[12], *b_cat = (const float*)d_in[13];
    const float* w_in  = (const float*)d_in[14], *b_in  = (const float*)d_in[15];
    const float* weight1 = (const float*)d_in[16], *root1 = (const float*)d_in[17], *bias1 = (const float*)d_in[18];
    const float* weight2 = (const float*)d_in[19], *root2 = (const float*)d_in[20], *bias2 = (const float*)d_in[21];
    const float* w_out = (const float*)d_in[22], *b_out = (const float*)d_in[23];
    float* outp = (float*)d_out;

    const int HSZ = HD * HD, PSZ = 768 * 64;

    // ---- workspace carve-up ----
    float* base  = (float*)d_ws;                       // [N,HD] f32
    u16*   hrelb = (u16*)(base + (size_t)NN * HD);     // [2,N,HD] bf16
    u16*   xh    = hrelb + (size_t)2 * NN * HD;
    u16*   xl    = xh + (size_t)NN * HD;
    u16*   yh    = xl + (size_t)NN * HD;
    u16*   yl    = yh + (size_t)NN * HD;
    int*   offs  = (int*)(yl + (size_t)NN * HD);
    int*   segc  = offs + (NSEG + 1);
    int*   srcl  = segc + NSEG;
    int*   bsum  = srcl + EE;
    int*   bbase = bsum + NB;
    uintptr_t wp = ((uintptr_t)(bbase + NB) + 15) & ~(uintptr_t)15;
    u16* desB = (u16*)wp;
    u16* twB  = desB + PSZ;
    u16* winB = twB + PSZ;
    u16* cat1 = winB + HSZ;
    u16* cat2 = cat1 + 3 * HSZ;

    // ---- CSR build ----
    hipMemsetAsync(segc, 0, NSEG * sizeof(int), stream);
    count_seg<<<(EE + 255) / 256, 256, 0, stream>>>(ei, et, segc);
    scan_local<<<NB, 256, 0, stream>>>(segc, offs, bsum);
    scan_bsum<<<1, 64, 0, stream>>>(bsum, bbase);
    add_base<<<(NSEG + 255) / 256, 256, 0, stream>>>(offs, bbase);
    hipMemsetAsync(segc, 0, NSEG * sizeof(int), stream);
    fill_src<<<(EE + 255) / 256, 256, 0, stream>>>(ei, et, offs, segc, srcl);

    // ---- weight conversion ----
    conv_wf<<<(PSZ + 255) / 256, 256, 0, stream>>>(w_des, desB);   // fragment-major
    conv_wf<<<(PSZ + 255) / 256, 256, 0, stream>>>(w_tw,  twB);    // fragment-major
    conv_w<<<(HSZ + 255) / 256, 256, 0, stream>>>(w_in, HD, HD, winB, 0);
    conv_w<<<(HSZ + 255) / 256, 256, 0, stream>>>(weight1,       HD, HD, cat1, 0);
    conv_w<<<(HSZ + 255) / 256, 256, 0, stream>>>(weight1 + HSZ, HD, HD, cat1, 256);
    conv_w<<<(HSZ + 255) / 256, 256, 0, stream>>>(root1,         HD, HD, cat1, 512);
    conv_w<<<(HSZ + 255) / 256, 256, 0, stream>>>(weight2,       HD, HD, cat2, 0);
    conv_w<<<(HSZ + 255) / 256, 256, 0, stream>>>(weight2 + HSZ, HD, HD, cat2, 256);
    conv_w<<<(HSZ + 255) / 256, 256, 0, stream>>>(root2,         HD, HD, cat2, 512);

    const int NYB = (NN + 127) / 128;    // 391 (128-row blocks)
    const int NWB = (NN + 31) / 32;      // 1563 (32-row blocks = 2 waves x 16 rows)

    // ---- fused feature projections (des+tweet) -> xh/xl (wave-autonomous, 128-thr) ----
    gemm_projW<<<2 * NWB, 128, 0, stream>>>(des, tweet, desB, twB, b_des, b_tw, xh, xl);
    dim3 gsmall(1, (NN + 63) / 64);
    gemm_f32s<64, 64, 8, 4, 4><<<gsmall, 256, 0, stream>>>(nump, 5, w_num, 64, b_num, xh, xl, 128, NN, 64, 5);
    gemm_f32s<64, 64, 8, 4, 4><<<gsmall, 256, 0, stream>>>(catp, 3, w_cat, 64, b_cat, xh, xl, 192, NN, 64, 3);

    // ---- y = lrelu(x @ w_in + b_in) -> yh/yl ----
    gemm_bf16L<1><<<2 * NYB, 256, 0, stream>>>(xh, xl, winB, b_in, yh, yl, nullptr, NN, 2);

    // ---- layer 1: fused [W_r0|W_r1|root1] -> hrelb (bf16) + base (f32) ----
    gemm_bf16L<2><<<6 * NYB, 256, 0, stream>>>(yh, yl, cat1, bias1, hrelb, nullptr, base, NN, 6);
    gather_mean_b<0><<<(NN + 3) / 4, 256, 0, stream>>>(hrelb, offs, srcl, base, xh, xl, nullptr, nullptr, nullptr);

    // ---- layer 2 + fused output head ----
    gemm_bf16L<2><<<6 * NYB, 256, 0, stream>>>(xh, xl, cat2, bias2, hrelb, nullptr, base, NN, 6);
    gather_mean_b<1><<<(NN + 3) / 4, 256, 0, stream>>>(hrelb, offs, srcl, base, nullptr, nullptr, w_out, b_out, outp);
}

// Round 16
// 549.213 us; speedup vs baseline: 1.8492x; 1.0789x over previous
//
#include <hip/hip_runtime.h>

#define NN 50000
#define EE 800000
#define HD 256
#define NSEG (2 * NN)
#define CHUNK 2048
#define NB ((NSEG + CHUNK - 1) / CHUNK)

typedef unsigned short u16;
typedef unsigned long long u64;
typedef short bf16x8 __attribute__((ext_vector_type(8)));
typedef float f32x4 __attribute__((ext_vector_type(4)));

__device__ __forceinline__ u16 f2bf_rne(float f) {
    unsigned u = __float_as_uint(f);
    return (u16)((u + 0x7FFF + ((u >> 16) & 1)) >> 16);
}
// trunc hi + RNE residual
__device__ __forceinline__ void split_tr(float v, u16& h, u16& l) {
    unsigned u = __float_as_uint(v);
    h = (u16)(u >> 16);
    l = f2bf_rne(v - __uint_as_float(u & 0xFFFF0000u));
}

// bijective XCD-chunked swizzle (m204)
__device__ __forceinline__ int xcd_swizzle(int orig, int nwg) {
    int q = nwg >> 3, r = nwg & 7;
    int xcd = orig & 7, idx = orig >> 3;
    return (xcd < r ? xcd * (q + 1) : r * (q + 1) + (xcd - r) * q) + idx;
}

// async global->LDS, 16B per lane
__device__ __forceinline__ void g2l16(const void* g, void* l) {
    __builtin_amdgcn_global_load_lds(
        (const __attribute__((address_space(1))) void*)g,
        (__attribute__((address_space(3))) void*)l, 16, 0, 0);
}

// bank swizzle for 64B-row bf16 tiles
__device__ __forceinline__ int swz2(int row) { return (row & 2) | ((row >> 2) & 1); }

// stage one 128x32 bf16 tile from G[rc][K] (k-contiguous), source-swizzled
__device__ __forceinline__ void stage_bf16(const u16* __restrict__ G, u16* S,
                                           int base_rc, int maxrc, int K, int k0, int tid) {
#pragma unroll
    for (int s = 0; s < 2; s++) {
        int slot = tid + s * 256;
        int row = slot >> 2, gg = slot & 3;
        int gsrc = gg ^ swz2(row);
        int arow = base_rc + row; arow = arow < maxrc ? arow : maxrc - 1;
        g2l16(G + (size_t)arow * K + k0 + gsrc * 8, S + ((tid & ~63) + s * 256) * 8);
    }
}

// ============ counted-vmcnt dbuf bf16 GEMM, single-pass: A bf16 [M][256], B bf16 ====
// acc = A*B. BM=BN=128, 4 waves 2x2, MFMA 16x16x32, k-map k=k0+g*8+j.
// Stage = 4 VMEM/thread -> steady-state wait vmcnt(4).
// MODE 1: lrelu -> bf16 out (w_in). MODE 2: relu; col<512 -> bf16 hrel; else f32 O2.
template<int MODE>
__global__ __launch_bounds__(256) void gemm_bf16s(
    const u16* __restrict__ Ag, const u16* __restrict__ Bg,
    const float* __restrict__ bias,
    u16* __restrict__ O1, float* __restrict__ O2,
    int M, int nxb)
{
    __shared__ __align__(16) u16 sA[2][128 * 32];
    __shared__ __align__(16) u16 sB[2][128 * 32];
    const int wgid = xcd_swizzle(blockIdx.x, gridDim.x);
    const int brow = (wgid / nxb) * 128, bcol = (wgid % nxb) * 128;
    const int tid = threadIdx.x, lane = tid & 63, w = tid >> 6;
    const int wr = w >> 1, wc = w & 1;
    const int r15 = lane & 15, g = lane >> 4;
    const int fsw = (g ^ swz2(r15)) * 8;

    f32x4 acc[4][4];
#pragma unroll
    for (int mi = 0; mi < 4; mi++)
#pragma unroll
        for (int ni = 0; ni < 4; ni++) acc[mi][ni] = (f32x4){0.f, 0.f, 0.f, 0.f};

    auto stage_step = [&](int k0, int b) {       // 4 VMEM instr per thread
        stage_bf16(Ag, sA[b], brow, M, 256, k0, tid);
        stage_bf16(Bg, sB[b], bcol, 1 << 30, 256, k0, tid);
    };
    auto compute_step = [&](int b) {
        bf16x8 af[4], bf[4];
#pragma unroll
        for (int mi = 0; mi < 4; mi++) {
            int idx = (wr * 64 + mi * 16 + r15) * 32 + fsw;
            af[mi] = *(const bf16x8*)&sA[b][idx];
        }
#pragma unroll
        for (int ni = 0; ni < 4; ni++) {
            int idx = (wc * 64 + ni * 16 + r15) * 32 + fsw;
            bf[ni] = *(const bf16x8*)&sB[b][idx];
        }
#pragma unroll
        for (int mi = 0; mi < 4; mi++)
#pragma unroll
            for (int ni = 0; ni < 4; ni++)
                acc[mi][ni] = __builtin_amdgcn_mfma_f32_16x16x32_bf16(af[mi], bf[ni], acc[mi][ni], 0, 0, 0);
    };

    stage_step(0, 0);
    stage_step(32, 1);
#pragma unroll
    for (int t = 0; t < 7; t++) {
        asm volatile("s_waitcnt vmcnt(4)" ::: "memory");   // drain buf[t&1] only
        __builtin_amdgcn_s_barrier();
        compute_step(t & 1);
        __builtin_amdgcn_s_barrier();
        if (t + 2 < 8) stage_step((t + 2) * 32, t & 1);
    }
    asm volatile("s_waitcnt vmcnt(0)" ::: "memory");
    __builtin_amdgcn_s_barrier();
    compute_step(1);

#pragma unroll
    for (int mi = 0; mi < 4; mi++) {
#pragma unroll
        for (int ni = 0; ni < 4; ni++) {
            int col = bcol + wc * 64 + ni * 16 + r15;
            float bsv = bias[col & (HD - 1)];
            int rbase = brow + wr * 64 + mi * 16 + g * 4;
#pragma unroll
            for (int r = 0; r < 4; r++) {
                int grow = rbase + r;
                if (grow >= M) continue;
                float v = acc[mi][ni][r] + bsv;
                if (MODE == 1) {
                    v = v > 0.f ? v : 0.01f * v;   // lrelu
                    O1[(size_t)grow * HD + col] = f2bf_rne(v);
                } else {
                    v = fmaxf(v, 0.f);             // relu
                    if (col < 2 * HD) {
                        O1[((size_t)(col >> 8) * NN + grow) * HD + (col & (HD - 1))] = f2bf_rne(v);
                    } else {
                        O2[(size_t)grow * HD + (col & (HD - 1))] = v;
                    }
                }
            }
        }
    }
}

// ===================== wave-autonomous dual-projection GEMM (K=768) =====================
// 128-thread blocks = 2 independent waves (no barriers). Each wave: 16 rows x 64 cols.
// A f32 coalesced->regs->perm-convert(hi/lo)->private LDS (dbuf, pad 40). B fragment-major.
// Internal math keeps hi/lo pair (protects layer-0 precision); OUTPUT bf16 hi only.
__global__ __launch_bounds__(128) void gemm_projW(
    const float* __restrict__ A0, const float* __restrict__ A1,
    const u16* __restrict__ B0, const u16* __restrict__ B1,
    const float* __restrict__ bias0, const float* __restrict__ bias1,
    u16* __restrict__ Ch)
{
    __shared__ __align__(16) u16 lds[2 * 2 * 2 * 640];   // [wave][buf][h/l][16*40]
    const int p = blockIdx.x & 1;
    const float* __restrict__ A = p ? A1 : A0;
    const u16* __restrict__ Bp = p ? B1 : B0;
    const float* __restrict__ bias = p ? bias1 : bias0;
    const int coff = p * 64;
    const int lane = threadIdx.x & 63, w = threadIdx.x >> 6;
    const int wrow = (blockIdx.x >> 1) * 32 + w * 16;
    const int r15 = lane & 15, g = lane >> 4;
    const int lbase = w * 2560;      // u16 units

    size_t aoff[2];
#pragma unroll
    for (int i = 0; i < 2; i++) {
        int row = wrow + (lane >> 3) + 8 * i;
        row = row < NN ? row : NN - 1;
        aoff[i] = (size_t)row * 768 + (lane & 7) * 4;
    }
    size_t boff[4];
#pragma unroll
    for (int ni = 0; ni < 4; ni++)
        boff[ni] = (size_t)(ni * 64 + lane) * 8;

    f32x4 acc[4];
#pragma unroll
    for (int ni = 0; ni < 4; ni++) acc[ni] = (f32x4){0.f, 0.f, 0.f, 0.f};

    float4 Ar0[2], Ar1[2];
    uint4 Bs0[4], Bs1[4];

    auto loadA = [&](int t, float4 (&d)[2]) {
#pragma unroll
        for (int i = 0; i < 2; i++) d[i] = *(const float4*)&A[aoff[i] + t * 32];
    };
    auto loadB = [&](int t, uint4 (&d)[4]) {
#pragma unroll
        for (int ni = 0; ni < 4; ni++) d[ni] = *(const uint4*)&Bp[boff[ni] + (size_t)t * 2048];
    };
    auto writeA = [&](const float4 (&s)[2], int buf) {
#pragma unroll
        for (int i = 0; i < 2; i++) {
            int row2 = (lane >> 3) + 8 * i;
            unsigned e0 = __float_as_uint(s[i].x), e1 = __float_as_uint(s[i].y),
                     e2 = __float_as_uint(s[i].z), e3 = __float_as_uint(s[i].w);
            unsigned h0 = __builtin_amdgcn_perm(e1, e0, 0x07060302u);
            unsigned h1 = __builtin_amdgcn_perm(e3, e2, 0x07060302u);
            unsigned q0 = __float_as_uint(s[i].x - __uint_as_float(e0 & 0xFFFF0000u));
            unsigned q1 = __float_as_uint(s[i].y - __uint_as_float(e1 & 0xFFFF0000u));
            unsigned q2 = __float_as_uint(s[i].z - __uint_as_float(e2 & 0xFFFF0000u));
            unsigned q3 = __float_as_uint(s[i].w - __uint_as_float(e3 & 0xFFFF0000u));
            unsigned l0 = __builtin_amdgcn_perm(q1, q0, 0x07060302u);
            unsigned l1 = __builtin_amdgcn_perm(q3, q2, 0x07060302u);
            int idx = lbase + buf * 1280 + row2 * 40 + (lane & 7) * 4;
            *(u64*)&lds[idx] = (u64)h0 | ((u64)h1 << 32);
            *(u64*)&lds[idx + 640] = (u64)l0 | ((u64)l1 << 32);
        }
    };
    auto compute = [&](int buf, const uint4 (&Bv)[4]) {
        bf16x8 afh, afl;
        {
            int idx = lbase + buf * 1280 + r15 * 40 + g * 8;
            afh = *(const bf16x8*)&lds[idx];
            afl = *(const bf16x8*)&lds[idx + 640];
        }
#pragma unroll
        for (int ni = 0; ni < 4; ni++) {
            bf16x8 bb = __builtin_bit_cast(bf16x8, Bv[ni]);
            acc[ni] = __builtin_amdgcn_mfma_f32_16x16x32_bf16(afh, bb, acc[ni], 0, 0, 0);
            acc[ni] = __builtin_amdgcn_mfma_f32_16x16x32_bf16(afl, bb, acc[ni], 0, 0, 0);
        }
    };

    // prologue (NT = 24)
    loadA(0, Ar0); loadB(0, Bs0);
    writeA(Ar0, 0);
    loadA(1, Ar1); loadB(1, Bs1);
    for (int tt = 0; tt < 11; ++tt) {
        int t0 = 2 * tt;
        loadA(t0 + 2, Ar0);
        compute(0, Bs0);
        loadB(t0 + 2, Bs0);
        writeA(Ar1, 1);
        loadA(t0 + 3, Ar1);
        compute(1, Bs1);
        loadB(t0 + 3, Bs1);
        writeA(Ar0, 0);
    }
    compute(0, Bs0);     // t=22
    writeA(Ar1, 1);      // tile 23 -> buf1
    compute(1, Bs1);     // t=23

    // ---- coalesced epilogue: acc -> wave-private LDS (h plane) -> 16B stores ----
    u16* tlh = &lds[lbase];          // 16 x 72 u16 (pad 8)
#pragma unroll
    for (int ni = 0; ni < 4; ni++) {
        int col = ni * 16 + r15;
        float bsv = bias[col];
#pragma unroll
        for (int r = 0; r < 4; r++) {
            int row = g * 4 + r;
            float v = acc[ni][r] + bsv;
            v = v > 0.f ? v : 0.01f * v;   // lrelu
            tlh[row * 72 + col] = f2bf_rne(v);
        }
    }
    asm volatile("s_waitcnt lgkmcnt(0)" ::: "memory");
    __builtin_amdgcn_sched_barrier(0);
    {
        int row = lane >> 2, cb = (lane & 3) * 16;
        int grow = wrow + row;
        if (grow < NN) {
#pragma unroll
            for (int j = 0; j < 2; j++) {
                uint4 hv = *(const uint4*)&tlh[row * 72 + cb + j * 8];
                *(uint4*)&Ch[(size_t)grow * HD + coff + cb + j * 8] = hv;
            }
        }
    }
}

// ---- weight RNE-round+transpose: W f32 [K][Ncol] -> T bf16 [colOff+n][K] ----
__global__ void conv_w(const float* __restrict__ W, int K, int Ncol,
                       u16* __restrict__ Th, int colOff)
{
    int i = blockIdx.x * 256 + threadIdx.x;
    if (i >= K * Ncol) return;
    int k = i / Ncol, n = i % Ncol;
    Th[(size_t)(colOff + n) * K + k] = f2bf_rne(W[i]);
}

// ---- projection weights -> fragment-major: Bf[((t*4+ni)*64+lane)*8+j], K=768, Ncol=64 ----
__global__ void conv_wf(const float* __restrict__ W, u16* __restrict__ Bf)
{
    int i = blockIdx.x * 256 + threadIdx.x;
    if (i >= 768 * 64) return;
    int k = i >> 6, n = i & 63;
    int t = k >> 5, kk = k & 31, g = kk >> 3, j = kk & 7;
    int lane = g * 16 + (n & 15), ni = n >> 4;
    Bf[(size_t)((t * 4 + ni) * 64 + lane) * 8 + j] = f2bf_rne(W[i]);
}

// ---------------- small f32 GEMM (K=5/3), bf16 out ----------------
template<int BM, int BN, int BK, int TM, int TN>
__global__ __launch_bounds__(256) void gemm_f32s(
    const float* __restrict__ A, int lda,
    const float* __restrict__ B, int ldb,
    const float* __restrict__ bias,
    u16* __restrict__ Ch, int coff,
    int M, int Ncol, int K)
{
    constexpr int TX = BN / TN;
    __shared__ float As[BK][BM + 4];
    __shared__ float Bs[BK][BN + 4];
    const int tid = threadIdx.x;
    const int tx = tid % TX, ty = tid / TX;
    const int brow = blockIdx.y * BM;
    const int bcol = blockIdx.x * BN;
    float acc[TM][TN];
#pragma unroll
    for (int i = 0; i < TM; i++)
#pragma unroll
        for (int j = 0; j < TN; j++) acc[i][j] = 0.f;
    for (int k0 = 0; k0 < K; k0 += BK) {
#pragma unroll
        for (int idx = tid; idx < BM * BK; idx += 256) {
            int m = idx / BK, k = idx % BK;
            int gr = brow + m, gk = k0 + k;
            As[k][m] = (gr < M && gk < K) ? A[(size_t)gr * lda + gk] : 0.f;
        }
#pragma unroll
        for (int idx = tid; idx < BK * BN; idx += 256) {
            int k = idx / BN, n = idx % BN;
            int gk = k0 + k, gc = bcol + n;
            Bs[k][n] = (gk < K && gc < Ncol) ? B[(size_t)gk * ldb + gc] : 0.f;
        }
        __syncthreads();
#pragma unroll
        for (int k = 0; k < BK; k++) {
            float a[TM], b[TN];
#pragma unroll
            for (int i = 0; i < TM; i++) a[i] = As[k][ty * TM + i];
#pragma unroll
            for (int j = 0; j < TN; j++) b[j] = Bs[k][tx * TN + j];
#pragma unroll
            for (int i = 0; i < TM; i++)
#pragma unroll
                for (int j = 0; j < TN; j++) acc[i][j] = fmaf(a[i], b[j], acc[i][j]);
        }
        __syncthreads();
    }
#pragma unroll
    for (int i = 0; i < TM; i++) {
        int gr = brow + ty * TM + i;
        if (gr >= M) continue;
#pragma unroll
        for (int j = 0; j < TN; j++) {
            int gc = bcol + tx * TN + j;
            if (gc >= Ncol) continue;
            float v = acc[i][j] + bias[gc];
            v = v > 0.f ? v : 0.01f * v;
            Ch[(size_t)gr * HD + coff + gc] = f2bf_rne(v);
        }
    }
}

// ---------------- CSR build ----------------
__global__ void count_seg(const int* __restrict__ ei, const int* __restrict__ et,
                          int* __restrict__ segc)
{
    int e = blockIdx.x * blockDim.x + threadIdx.x;
    if (e < EE) {
        int dst = ei[EE + e];
        int r = et[e];
        atomicAdd(&segc[r * NN + dst], 1);
    }
}

__global__ __launch_bounds__(256) void scan_local(const int* __restrict__ segc,
                                                  int* __restrict__ offs,
                                                  int* __restrict__ bsum)
{
    int b = blockIdx.x;
    int base = b * CHUNK;
    int tid = threadIdx.x;
    int lane = tid & 63, wave = tid >> 6;
    __shared__ int wsum[4];
    int vals[8];
    int i0 = base + tid * 8;
    int s = 0;
    if (i0 + 7 < NSEG) {
        int4 v0 = *(const int4*)&segc[i0];
        int4 v1 = *(const int4*)&segc[i0 + 4];
        vals[0] = v0.x; vals[1] = v0.y; vals[2] = v0.z; vals[3] = v0.w;
        vals[4] = v1.x; vals[5] = v1.y; vals[6] = v1.z; vals[7] = v1.w;
    } else {
#pragma unroll
        for (int j = 0; j < 8; j++) vals[j] = (i0 + j < NSEG) ? segc[i0 + j] : 0;
    }
#pragma unroll
    for (int j = 0; j < 8; j++) s += vals[j];
    int v = s;
#pragma unroll
    for (int off = 1; off < 64; off <<= 1) {
        int u = __shfl_up(v, off);
        if (lane >= off) v += u;
    }
    if (lane == 63) wsum[wave] = v;
    __syncthreads();
    int wbase = 0;
#pragma unroll
    for (int ww = 0; ww < 4; ww++) if (ww < wave) wbase += wsum[ww];
    int run = wbase + v - s;
#pragma unroll
    for (int j = 0; j < 8; j++) {
        run += vals[j];
        int i = i0 + j;
        if (i < NSEG) offs[i + 1] = run;
    }
    if (tid == 0) {
        int t = 0;
#pragma unroll
        for (int ww = 0; ww < 4; ww++) t += wsum[ww];
        bsum[b] = t;
    }
}

__global__ void scan_bsum(const int* __restrict__ bsum, int* __restrict__ bbase)
{
    int lane = threadIdx.x;
    int c = (lane < NB) ? bsum[lane] : 0;
    int v = c;
#pragma unroll
    for (int off = 1; off < 64; off <<= 1) {
        int u = __shfl_up(v, off);
        if (lane >= off) v += u;
    }
    if (lane < NB) bbase[lane] = v - c;
}

__global__ void add_base(int* __restrict__ offs, const int* __restrict__ bbase)
{
    int i = blockIdx.x * blockDim.x + threadIdx.x;
    if (i < NSEG) offs[i + 1] += bbase[i / CHUNK];
    if (i == 0) offs[0] = 0;
}

__global__ void fill_src(const int* __restrict__ ei, const int* __restrict__ et,
                         const int* __restrict__ offs, int* __restrict__ cursor,
                         int* __restrict__ src_list)
{
    int e = blockIdx.x * blockDim.x + threadIdx.x;
    if (e < EE) {
        int src = ei[e];
        int dst = ei[EE + e];
        int s = et[e] * NN + dst;
        int pos = offs[s] + atomicAdd(&cursor[s], 1);
        src_list[pos] = src;
    }
}

// ---------------- gather: v = base + sum_r mean(hrel_bf16) ----------------
// OUTM 0: write bf16 (next layer input).  OUTM 1: fused head -> logits.
template<int OUTM>
__global__ __launch_bounds__(256) void gather_mean_b(
    const u16* __restrict__ hrelb,
    const int* __restrict__ offs,
    const int* __restrict__ src_list,
    const float* __restrict__ basein,
    u16* __restrict__ Oh,
    const float* __restrict__ wout, const float* __restrict__ bout,
    float* __restrict__ logits)
{
    int d = blockIdx.x * 4 + (threadIdx.x >> 6);
    if (d >= NN) return;
    int lane = threadIdx.x & 63;
    f32x4 acc = {0.f, 0.f, 0.f, 0.f};
#pragma unroll
    for (int r = 0; r < 2; r++) {
        int s = r * NN + d;
        int start = offs[s], end = offs[s + 1];
        if (start == end) continue;
        f32x4 a = {0.f, 0.f, 0.f, 0.f};
        const u16* hb = hrelb + (size_t)r * NN * HD;
        for (int i = start; i < end; i++) {
            int src = src_list[i];
            uint2 wv = *(const uint2*)(hb + (size_t)src * HD + lane * 4);
            a.x += __uint_as_float(wv.x << 16);
            a.y += __uint_as_float(wv.x & 0xFFFF0000u);
            a.z += __uint_as_float(wv.y << 16);
            a.w += __uint_as_float(wv.y & 0xFFFF0000u);
        }
        float inv = 1.0f / (float)(end - start);
        acc.x += a.x * inv; acc.y += a.y * inv;
        acc.z += a.z * inv; acc.w += a.w * inv;
    }
    float4 b = ((const float4*)(basein + (size_t)d * HD))[lane];
    float v0 = b.x + acc.x, v1 = b.y + acc.y, v2 = b.z + acc.z, v3 = b.w + acc.w;
    if (OUTM == 0) {
        uint2 uh;
        uh.x = (unsigned)f2bf_rne(v0) | ((unsigned)f2bf_rne(v1) << 16);
        uh.y = (unsigned)f2bf_rne(v2) | ((unsigned)f2bf_rne(v3) << 16);
        *(uint2*)(Oh + (size_t)d * HD + lane * 4) = uh;
    } else {
        int k = lane * 4;
        float a0 = v0 * wout[(k + 0) * 2 + 0] + v1 * wout[(k + 1) * 2 + 0]
                 + v2 * wout[(k + 2) * 2 + 0] + v3 * wout[(k + 3) * 2 + 0];
        float a1 = v0 * wout[(k + 0) * 2 + 1] + v1 * wout[(k + 1) * 2 + 1]
                 + v2 * wout[(k + 2) * 2 + 1] + v3 * wout[(k + 3) * 2 + 1];
#pragma unroll
        for (int off = 32; off > 0; off >>= 1) {
            a0 += __shfl_down(a0, off);
            a1 += __shfl_down(a1, off);
        }
        if (lane == 0) {
            logits[(size_t)d * 2 + 0] = a0 + bout[0];
            logits[(size_t)d * 2 + 1] = a1 + bout[1];
        }
    }
}

extern "C" void kernel_launch(void* const* d_in, const int* in_sizes, int n_in,
                              void* d_out, int out_size, void* d_ws, size_t ws_size,
                              hipStream_t stream)
{
    const float* des   = (const float*)d_in[0];
    const float* tweet = (const float*)d_in[1];
    const float* nump  = (const float*)d_in[2];
    const float* catp  = (const float*)d_in[3];
    const int*   ei    = (const int*)d_in[4];
    const int*   et    = (const int*)d_in[5];
    const float* w_des = (const float*)d_in[6],  *b_des = (const float*)d_in[7];
    const float* w_tw  = (const float*)d_in[8],  *b_tw  = (const float*)d_in[9];
    const float* w_num = (const float*)d_in[10], *b_num = (const float*)d_in[11];
    const float* w_cat = (const float*)d_in[12], *b_cat = (const float*)d_in[13];
    const float* w_in  = (const float*)d_in[14], *b_in  = (const float*)d_in[15];
    const float* weight1 = (const float*)d_in[16], *root1 = (const float*)d_in[17], *bias1 = (const float*)d_in[18];
    const float* weight2 = (const float*)d_in[19], *root2 = (const float*)d_in[20], *bias2 = (const float*)d_in[21];
    const float* w_out = (const float*)d_in[22], *b_out = (const float*)d_in[23];
    float* outp = (float*)d_out;

    const int HSZ = HD * HD, PSZ = 768 * 64;

    // ---- workspace carve-up ----
    float* base  = (float*)d_ws;                       // [N,HD] f32
    u16*   hrelb = (u16*)(base + (size_t)NN * HD);     // [2,N,HD] bf16
    u16*   xh    = hrelb + (size_t)2 * NN * HD;        // [N,HD] bf16
    u16*   yh    = xh + (size_t)NN * HD;               // [N,HD] bf16
    int*   offs  = (int*)(yh + (size_t)NN * HD);
    int*   segc  = offs + (NSEG + 1);
    int*   srcl  = segc + NSEG;
    int*   bsum  = srcl + EE;
    int*   bbase = bsum + NB;
    uintptr_t wp = ((uintptr_t)(bbase + NB) + 15) & ~(uintptr_t)15;
    u16* desB = (u16*)wp;
    u16* twB  = desB + PSZ;
    u16* winB = twB + PSZ;
    u16* cat1 = winB + HSZ;
    u16* cat2 = cat1 + 3 * HSZ;

    // ---- CSR build ----
    hipMemsetAsync(segc, 0, NSEG * sizeof(int), stream);
    count_seg<<<(EE + 255) / 256, 256, 0, stream>>>(ei, et, segc);
    scan_local<<<NB, 256, 0, stream>>>(segc, offs, bsum);
    scan_bsum<<<1, 64, 0, stream>>>(bsum, bbase);
    add_base<<<(NSEG + 255) / 256, 256, 0, stream>>>(offs, bbase);
    hipMemsetAsync(segc, 0, NSEG * sizeof(int), stream);
    fill_src<<<(EE + 255) / 256, 256, 0, stream>>>(ei, et, offs, segc, srcl);

    // ---- weight conversion ----
    conv_wf<<<(PSZ + 255) / 256, 256, 0, stream>>>(w_des, desB);   // fragment-major
    conv_wf<<<(PSZ + 255) / 256, 256, 0, stream>>>(w_tw,  twB);    // fragment-major
    conv_w<<<(HSZ + 255) / 256, 256, 0, stream>>>(w_in, HD, HD, winB, 0);
    conv_w<<<(HSZ + 255) / 256, 256, 0, stream>>>(weight1,       HD, HD, cat1, 0);
    conv_w<<<(HSZ + 255) / 256, 256, 0, stream>>>(weight1 + HSZ, HD, HD, cat1, 256);
    conv_w<<<(HSZ + 255) / 256, 256, 0, stream>>>(root1,         HD, HD, cat1, 512);
    conv_w<<<(HSZ + 255) / 256, 256, 0, stream>>>(weight2,       HD, HD, cat2, 0);
    conv_w<<<(HSZ + 255) / 256, 256, 0, stream>>>(weight2 + HSZ, HD, HD, cat2, 256);
    conv_w<<<(HSZ + 255) / 256, 256, 0, stream>>>(root2,         HD, HD, cat2, 512);

    const int NYB = (NN + 127) / 128;    // 391 (128-row blocks)
    const int NWB = (NN + 31) / 32;      // 1563 (32-row blocks = 2 waves x 16 rows)

    // ---- fused feature projections (des+tweet) -> xh ----
    gemm_projW<<<2 * NWB, 128, 0, stream>>>(des, tweet, desB, twB, b_des, b_tw, xh);
    dim3 gsmall(1, (NN + 63) / 64);
    gemm_f32s<64, 64, 8, 4, 4><<<gsmall, 256, 0, stream>>>(nump, 5, w_num, 64, b_num, xh, 128, NN, 64, 5);
    gemm_f32s<64, 64, 8, 4, 4><<<gsmall, 256, 0, stream>>>(catp, 3, w_cat, 64, b_cat, xh, 192, NN, 64, 3);

    // ---- y = lrelu(x @ w_in + b_in) -> yh ----
    gemm_bf16s<1><<<2 * NYB, 256, 0, stream>>>(xh, winB, b_in, yh, nullptr, NN, 2);

    // ---- layer 1: fused [W_r0|W_r1|root1] -> hrelb (bf16) + base (f32) ----
    gemm_bf16s<2><<<6 * NYB, 256, 0, stream>>>(yh, cat1, bias1, hrelb, base, NN, 6);
    gather_mean_b<0><<<(NN + 3) / 4, 256, 0, stream>>>(hrelb, offs, srcl, base, xh, nullptr, nullptr, nullptr);

    // ---- layer 2 + fused output head ----
    gemm_bf16s<2><<<6 * NYB, 256, 0, stream>>>(xh, cat2, bias2, hrelb, base, NN, 6);
    gather_mean_b<1><<<(NN + 3) / 4, 256, 0, stream>>>(hrelb, offs, srcl, base, nullptr, w_out, b_out, outp);
}